// Round 3
// baseline (497.799 us; speedup 1.0000x reference)
//
#include <hip/hip_runtime.h>

#define KS 3
#define CIN 64
#define OC 18          // 2*3*3
#define NB 4
#define H 256
#define W 256
#define OH 128
#define OW 128
#define EPS 1e-5f

#define TS 16          // conv tile
#define HALO 18        // TS + 2
#define NELEM (HALO * HALO)   // 324
#define XPITCH 24      // LDS row pitch: ty*24 mod 32 = {0,24,16,8} -> uniform 2-way (free)
#define SLOT (HALO * XPITCH)  // 432 floats per channel slot
#define CHUNK 8
#define NCHUNK (CIN / CHUNK)

// ws layout (floats):
//   [0..17]    sum      [18..35] sumsq    [36..53] scale    [54..71] shift
//   [256 ...]  sigma_s [NB][OC][OH][OW]  (1,179,648 floats)  — strided-pixel sigma
//   then       wr: repacked weights [CIN][OC][16]  (18,432 floats)

__device__ __forceinline__ int refl(int i, int n) {
    if (i < 0) i = -i;
    if (i >= n) i = 2 * n - 2 - i;
    return i;
}

// ---------------------------------------------------------------------------
// repack weights: wgt[(oc*CIN+ci)*9 + k] -> wr[(ci*OC+oc)*16 + k]  (pad to 16)
// ---------------------------------------------------------------------------
__global__ void repack_w(const float* __restrict__ wgt, float* __restrict__ wr)
{
    int i = blockIdx.x * 256 + threadIdx.x;
    if (i < CIN * OC * 16) {
        int k = i & 15, cioc = i >> 4;
        int oc = cioc % OC, ci = cioc / OC;
        wr[i] = (k < 9) ? wgt[(oc * CIN + ci) * 9 + k] : 0.f;
    }
}

// ---------------------------------------------------------------------------
// Kernel A: conv + fused BN-stats + strided sigma store
// 16x16 tile, 256 threads, 1 px/thread. 8-channel staging chunks,
// double-buffered LDS, register prefetch one full chunk ahead.
// ---------------------------------------------------------------------------
__global__ __launch_bounds__(256) void conv_kernel(
        const float* __restrict__ x, const float* __restrict__ wr,
        float* __restrict__ sigma_s, float* __restrict__ stats)
{
    __shared__ float xt[2][CHUNK][SLOT];   // 2*8*432*4 = 27.6 KB
    __shared__ float sred[36];

    const int tid = threadIdx.x;
    const int tx = tid & 15, ty = tid >> 4;
    const int h0 = blockIdx.y * TS, w0 = blockIdx.x * TS;
    const int n = blockIdx.z;

    if (tid < 36) sred[tid] = 0.f;

    // staging map: element i -> global offset g / lds offset l (i0=tid, i1=tid+256)
    int g0, l0, g1 = 0, l1 = 0;
    {
        int r = tid / HALO, c = tid - r * HALO;
        g0 = refl(h0 + r - 1, H) * W + refl(w0 + c - 1, W);
        l0 = r * XPITCH + c;
    }
    const bool v1 = (tid + 256) < NELEM;
    if (v1) {
        int i = tid + 256, r = i / HALO, c = i - r * HALO;
        g1 = refl(h0 + r - 1, H) * W + refl(w0 + c - 1, W);
        l1 = r * XPITCH + c;
    }

    const float* xn = x + (size_t)n * CIN * H * W;

    float pf0[CHUNK], pf1[CHUNK];
    // load chunk 0
#pragma unroll
    for (int cc = 0; cc < CHUNK; cc++) {
        const float* xp = xn + (size_t)cc * H * W;
        pf0[cc] = xp[g0];
        pf1[cc] = v1 ? xp[g1] : 0.f;
    }
    // write chunk 0 to buf0
#pragma unroll
    for (int cc = 0; cc < CHUNK; cc++) {
        xt[0][cc][l0] = pf0[cc];
        if (v1) xt[0][cc][l1] = pf1[cc];
    }
    // issue chunk 1 loads (in flight across the barrier)
#pragma unroll
    for (int cc = 0; cc < CHUNK; cc++) {
        const float* xp = xn + (size_t)(CHUNK + cc) * H * W;
        pf0[cc] = xp[g0];
        pf1[cc] = v1 ? xp[g1] : 0.f;
    }

    float acc[OC];
#pragma unroll
    for (int oc = 0; oc < OC; oc++) acc[oc] = 0.f;

    __syncthreads();

    for (int ch = 0; ch < NCHUNK; ch++) {
        const float* bufb = &xt[ch & 1][0][0];
        const float* wch = wr + ch * CHUNK * OC * 16;
#pragma unroll
        for (int cc = 0; cc < CHUNK; cc++) {
            float xw[9];
            const float* bs = bufb + cc * SLOT + ty * XPITCH + tx;
#pragma unroll
            for (int kh = 0; kh < 3; kh++)
#pragma unroll
                for (int kw = 0; kw < 3; kw++)
                    xw[kh * 3 + kw] = bs[kh * XPITCH + kw];
            const float* wc = wch + cc * OC * 16;
#pragma unroll
            for (int oc = 0; oc < OC; oc++) {
                const float* wp = wc + oc * 16;   // block-uniform -> s_load
#pragma unroll
                for (int k = 0; k < 9; k++)
                    acc[oc] = fmaf(xw[k], wp[k], acc[oc]);
            }
        }
        if (ch + 1 < NCHUNK) {
            float* bufn = &xt[(ch + 1) & 1][0][0];
#pragma unroll
            for (int cc = 0; cc < CHUNK; cc++) {
                bufn[cc * SLOT + l0] = pf0[cc];
                if (v1) bufn[cc * SLOT + l1] = pf1[cc];
            }
            if (ch + 2 < NCHUNK) {
#pragma unroll
                for (int cc = 0; cc < CHUNK; cc++) {
                    const float* xp = xn + (size_t)((ch + 2) * CHUNK + cc) * H * W;
                    pf0[cc] = xp[g0];
                    pf1[cc] = v1 ? xp[g1] : 0.f;
                }
            }
        }
        __syncthreads();
    }

    // fused BN stats: wave shuffle-reduce -> LDS -> 36 global atomics per block
#pragma unroll
    for (int oc = 0; oc < OC; oc++) {
        float v = acc[oc];
        float s = v, ss = v * v;
#pragma unroll
        for (int off = 32; off > 0; off >>= 1) {
            s  += __shfl_down(s, off);
            ss += __shfl_down(ss, off);
        }
        if ((tid & 63) == 0) {
            atomicAdd(&sred[oc], s);
            atomicAdd(&sred[18 + oc], ss);
        }
    }
    __syncthreads();
    if (tid < 36) atomicAdd(&stats[tid], sred[tid]);

    // store sigma only at strided (even,even) pixels, [NB][OC][OH][OW]
    if (!(ty & 1) && !(tx & 1)) {
        int oy = (h0 + ty) >> 1, ox = (w0 + tx) >> 1;
#pragma unroll
        for (int oc = 0; oc < OC; oc++)
            sigma_s[((size_t)(n * OC + oc) * OH + oy) * OW + ox] = acc[oc];
    }
}

// ---------------------------------------------------------------------------
// Kernel B: finalize BN -> scale/shift
// ---------------------------------------------------------------------------
__global__ void bn_kernel(const float* __restrict__ gamma,
                          const float* __restrict__ beta,
                          float* __restrict__ stats)
{
    int t = threadIdx.x;
    if (t < OC) {
        float cnt = (float)NB * H * W;
        float mean = stats[t] / cnt;
        float var  = stats[18 + t] / cnt - mean * mean;
        float sc   = gamma[t] * rsqrtf(var + EPS);
        stats[36 + t] = sc;
        stats[54 + t] = beta[t] - mean * sc;
    }
}

// ---------------------------------------------------------------------------
// Kernel C: BN-affine + softmax(18) + 9-tap adaptive aggregation
// ---------------------------------------------------------------------------
__global__ __launch_bounds__(256) void out_kernel(
        const float* __restrict__ x, const float* __restrict__ sigma_s,
        const float* __restrict__ stats, float* __restrict__ out)
{
    __shared__ float p_lds[OC][OW];   // 9 KB

    const int oh = blockIdx.x;
    const int n  = blockIdx.y >> 2;
    const int c0 = (blockIdx.y & 3) * 16;
    const int h  = 2 * oh;
    const int tid = threadIdx.x;

    for (int i = tid; i < OC * OW; i += 256) {
        int chn = i >> 7, ow = i & 127;
        float v = sigma_s[((size_t)(n * OC + chn) * OH + oh) * OW + ow];
        p_lds[chn][ow] = v * stats[36 + chn] + stats[54 + chn];
    }
    __syncthreads();

    if (tid < OW) {
        int ow = tid;
        float m = -1e30f;
#pragma unroll
        for (int chn = 0; chn < OC; chn++) m = fmaxf(m, p_lds[chn][ow]);
        float e[OC], sum = 0.f;
#pragma unroll
        for (int chn = 0; chn < OC; chn++) { e[chn] = __expf(p_lds[chn][ow] - m); sum += e[chn]; }
        float inv = 1.f / sum;
#pragma unroll
        for (int chn = 0; chn < OC; chn++) p_lds[chn][ow] = e[chn] * inv;
    }
    __syncthreads();

    const int ow = tid & 127, cl = tid >> 7;
    for (int it = 0; it < 8; it++) {
        int c = c0 + it * 2 + cl;
        int g = c >> 5;
        const float* xb = x + (size_t)(n * CIN + c) * H * W;
        float a = 0.f;
#pragma unroll
        for (int kh = 0; kh < 3; kh++) {
            int ih = refl(h - 1 + kh, H);
#pragma unroll
            for (int kw = 0; kw < 3; kw++) {
                int iw = refl(2 * ow - 1 + kw, W);
                a = fmaf(xb[ih * W + iw], p_lds[g * 9 + kh * 3 + kw][ow], a);
            }
        }
        out[((size_t)(n * CIN + c) * OH + oh) * OW + ow] = a;
    }
}

// ---------------------------------------------------------------------------
extern "C" void kernel_launch(void* const* d_in, const int* in_sizes, int n_in,
                              void* d_out, int out_size, void* d_ws, size_t ws_size,
                              hipStream_t stream) {
    const float* x     = (const float*)d_in[0];
    const float* cw    = (const float*)d_in[1];
    const float* gamma = (const float*)d_in[2];
    const float* beta  = (const float*)d_in[3];
    float* out = (float*)d_out;
    float* ws  = (float*)d_ws;

    float* stats   = ws;                        // 256 floats
    float* sigma_s = ws + 256;                  // NB*OC*OH*OW = 1,179,648 floats
    float* wrpk    = sigma_s + (size_t)NB * OC * OH * OW;  // 18,432 floats

    hipMemsetAsync(stats, 0, 256 * sizeof(float), stream);

    repack_w<<<(CIN * OC * 16 + 255) / 256, 256, 0, stream>>>(cw, wrpk);

    dim3 gA(W / TS, H / TS, NB);
    conv_kernel<<<gA, 256, 0, stream>>>(x, wrpk, sigma_s, stats);

    bn_kernel<<<1, 64, 0, stream>>>(gamma, beta, stats);

    dim3 gC(OH, NB * 4);
    out_kernel<<<gC, 256, 0, stream>>>(x, sigma_s, stats, out);
}

// Round 4
// 204.817 us; speedup vs baseline: 2.4305x; 2.4305x over previous
//
#include <hip/hip_runtime.h>

#define KS 3
#define CIN 64
#define OC 18          // 2*3*3
#define OCB 9          // oc per conv block (oc-split x2)
#define NB 4
#define H 256
#define W 256
#define OH 128
#define OW 128
#define EPS 1e-5f

#define TS 16          // conv tile
#define HALO 18        // TS + 2
#define NELEM (HALO * HALO)   // 324
#define XPITCH 24      // ty*24 mod 32 = {0,24,16,8} -> uniform 2-way (free)
#define SLOT (HALO * XPITCH)  // 432 floats

// ws layout (floats):
//   [0..17]    sum      [18..35] sumsq    [36..53] scale    [54..71] shift
//   [256 ...]  sigma_s [NB][OC][OH][OW]  (1,179,648 floats)
//   then       wr: repacked weights [CIN][OC][16]  (18,432 floats)

__device__ __forceinline__ int refl(int i, int n) {
    if (i < 0) i = -i;
    if (i >= n) i = 2 * n - 2 - i;
    return i;
}

// ---------------------------------------------------------------------------
// repack weights: wgt[(oc*CIN+ci)*9 + k] -> wr[(ci*OC+oc)*16 + k]  (pad to 16)
// ---------------------------------------------------------------------------
__global__ void repack_w(const float* __restrict__ wgt, float* __restrict__ wr)
{
    int i = blockIdx.x * 256 + threadIdx.x;
    if (i < CIN * OC * 16) {
        int k = i & 15, cioc = i >> 4;
        int oc = cioc % OC, ci = cioc / OC;
        wr[i] = (k < 9) ? wgt[(oc * CIN + ci) * 9 + k] : 0.f;
    }
}

// ---------------------------------------------------------------------------
// Kernel A: conv + fused BN-stats + strided sigma store.
// 16x16 tile, 256 threads, 1 px/thread, 9 output channels per block
// (half = blockIdx.x & 1). Double-buffered LDS, ONE barrier per channel,
// 2-deep statically-named register prefetch (unroll-by-2).
// ---------------------------------------------------------------------------
__global__ __launch_bounds__(256) void conv_kernel(
        const float* __restrict__ x, const float* __restrict__ wr,
        float* __restrict__ sigma_s, float* __restrict__ stats)
{
    __shared__ float xt[2][SLOT];     // 3.5 KB
    __shared__ float sred[2 * OCB];

    const int tid = threadIdx.x;
    const int tx = tid & 15, ty = tid >> 4;
    const int half = blockIdx.x & 1;
    const int h0 = blockIdx.y * TS, w0 = (blockIdx.x >> 1) * TS;
    const int n = blockIdx.z;

    if (tid < 2 * OCB) sred[tid] = 0.f;

    // staging map: element i -> global offset g / lds offset l (i0=tid, i1=tid+256)
    int g0, l0, g1 = 0, l1 = 0;
    {
        int r = tid / HALO, c = tid - r * HALO;
        g0 = refl(h0 + r - 1, H) * W + refl(w0 + c - 1, W);
        l0 = r * XPITCH + c;
    }
    const bool v1 = (tid + 256) < NELEM;
    if (v1) {
        int i = tid + 256, r = i / HALO, c = i - r * HALO;
        g1 = refl(h0 + r - 1, H) * W + refl(w0 + c - 1, W);
        l1 = r * XPITCH + c;
    }

    const float* xn = x + (size_t)n * CIN * H * W;

    // 2-deep prefetch, statically named regs
    float a0 = xn[g0];
    float b0 = v1 ? xn[g1] : 0.f;
    const float* xp1 = xn + H * W;
    float a1 = xp1[g0];
    float b1 = v1 ? xp1[g1] : 0.f;

    float acc[OCB];
#pragma unroll
    for (int oc = 0; oc < OCB; oc++) acc[oc] = 0.f;

    const int wbase0 = half * OCB * 16;   // offset of this block's oc range

#pragma unroll 1
    for (int p = 0; p < CIN / 2; p++) {
        const int ci0 = 2 * p;

        // ---- even channel: write buf0, refill prefetch A (for ci0+2) ----
        xt[0][l0] = a0;
        if (v1) xt[0][l1] = b0;
        if (ci0 + 2 < CIN) {
            const float* xp = xn + (size_t)(ci0 + 2) * H * W;
            a0 = xp[g0];
            b0 = v1 ? xp[g1] : 0.f;
        }
        __syncthreads();
        {
            float xw[9];
            const float* bs = &xt[0][ty * XPITCH + tx];
#pragma unroll
            for (int kh = 0; kh < 3; kh++)
#pragma unroll
                for (int kw = 0; kw < 3; kw++)
                    xw[kh * 3 + kw] = bs[kh * XPITCH + kw];
            const float* wc = wr + ci0 * OC * 16 + wbase0;
#pragma unroll
            for (int oc = 0; oc < OCB; oc++) {
                const float* wp = wc + oc * 16;   // block-uniform -> s_load
#pragma unroll
                for (int k = 0; k < 9; k++)
                    acc[oc] = fmaf(xw[k], wp[k], acc[oc]);
            }
        }

        // ---- odd channel: write buf1, refill prefetch B (for ci0+3) ----
        xt[1][l0] = a1;
        if (v1) xt[1][l1] = b1;
        if (ci0 + 3 < CIN) {
            const float* xp = xn + (size_t)(ci0 + 3) * H * W;
            a1 = xp[g0];
            b1 = v1 ? xp[g1] : 0.f;
        }
        __syncthreads();
        {
            float xw[9];
            const float* bs = &xt[1][ty * XPITCH + tx];
#pragma unroll
            for (int kh = 0; kh < 3; kh++)
#pragma unroll
                for (int kw = 0; kw < 3; kw++)
                    xw[kh * 3 + kw] = bs[kh * XPITCH + kw];
            const float* wc = wr + (ci0 + 1) * OC * 16 + wbase0;
#pragma unroll
            for (int oc = 0; oc < OCB; oc++) {
                const float* wp = wc + oc * 16;
#pragma unroll
                for (int k = 0; k < 9; k++)
                    acc[oc] = fmaf(xw[k], wp[k], acc[oc]);
            }
        }
        __syncthreads();
    }

    // fused BN stats: wave shuffle-reduce -> LDS -> 18 global atomics per block
#pragma unroll
    for (int oc = 0; oc < OCB; oc++) {
        float v = acc[oc];
        float s = v, ss = v * v;
#pragma unroll
        for (int off = 32; off > 0; off >>= 1) {
            s  += __shfl_down(s, off);
            ss += __shfl_down(ss, off);
        }
        if ((tid & 63) == 0) {
            atomicAdd(&sred[oc], s);
            atomicAdd(&sred[OCB + oc], ss);
        }
    }
    __syncthreads();
    if (tid < 2 * OCB) {
        int gidx = (tid < OCB) ? (half * OCB + tid) : (18 + half * OCB + tid - OCB);
        atomicAdd(&stats[gidx], sred[tid]);
    }

    // store sigma only at strided (even,even) pixels, [NB][OC][OH][OW]
    if (!(ty & 1) && !(tx & 1)) {
        int oy = (h0 + ty) >> 1, ox = (w0 + tx) >> 1;
#pragma unroll
        for (int oc = 0; oc < OCB; oc++)
            sigma_s[((size_t)(n * OC + half * OCB + oc) * OH + oy) * OW + ox] = acc[oc];
    }
}

// ---------------------------------------------------------------------------
// Kernel B: finalize BN -> scale/shift
// ---------------------------------------------------------------------------
__global__ void bn_kernel(const float* __restrict__ gamma,
                          const float* __restrict__ beta,
                          float* __restrict__ stats)
{
    int t = threadIdx.x;
    if (t < OC) {
        float cnt = (float)NB * H * W;
        float mean = stats[t] / cnt;
        float var  = stats[18 + t] / cnt - mean * mean;
        float sc   = gamma[t] * rsqrtf(var + EPS);
        stats[36 + t] = sc;
        stats[54 + t] = beta[t] - mean * sc;
    }
}

// ---------------------------------------------------------------------------
// Kernel C: BN-affine + softmax(18) + 9-tap adaptive aggregation
// ---------------------------------------------------------------------------
__global__ __launch_bounds__(256) void out_kernel(
        const float* __restrict__ x, const float* __restrict__ sigma_s,
        const float* __restrict__ stats, float* __restrict__ out)
{
    __shared__ float p_lds[OC][OW];   // 9 KB

    const int oh = blockIdx.x;
    const int n  = blockIdx.y >> 2;
    const int c0 = (blockIdx.y & 3) * 16;
    const int h  = 2 * oh;
    const int tid = threadIdx.x;

    for (int i = tid; i < OC * OW; i += 256) {
        int chn = i >> 7, ow = i & 127;
        float v = sigma_s[((size_t)(n * OC + chn) * OH + oh) * OW + ow];
        p_lds[chn][ow] = v * stats[36 + chn] + stats[54 + chn];
    }
    __syncthreads();

    if (tid < OW) {
        int ow = tid;
        float m = -1e30f;
#pragma unroll
        for (int chn = 0; chn < OC; chn++) m = fmaxf(m, p_lds[chn][ow]);
        float e[OC], sum = 0.f;
#pragma unroll
        for (int chn = 0; chn < OC; chn++) { e[chn] = __expf(p_lds[chn][ow] - m); sum += e[chn]; }
        float inv = 1.f / sum;
#pragma unroll
        for (int chn = 0; chn < OC; chn++) p_lds[chn][ow] = e[chn] * inv;
    }
    __syncthreads();

    const int ow = tid & 127, cl = tid >> 7;
    for (int it = 0; it < 8; it++) {
        int c = c0 + it * 2 + cl;
        int g = c >> 5;
        const float* xb = x + (size_t)(n * CIN + c) * H * W;
        float a = 0.f;
#pragma unroll
        for (int kh = 0; kh < 3; kh++) {
            int ih = refl(h - 1 + kh, H);
#pragma unroll
            for (int kw = 0; kw < 3; kw++) {
                int iw = refl(2 * ow - 1 + kw, W);
                a = fmaf(xb[ih * W + iw], p_lds[g * 9 + kh * 3 + kw][ow], a);
            }
        }
        out[((size_t)(n * CIN + c) * OH + oh) * OW + ow] = a;
    }
}

// ---------------------------------------------------------------------------
extern "C" void kernel_launch(void* const* d_in, const int* in_sizes, int n_in,
                              void* d_out, int out_size, void* d_ws, size_t ws_size,
                              hipStream_t stream) {
    const float* x     = (const float*)d_in[0];
    const float* cw    = (const float*)d_in[1];
    const float* gamma = (const float*)d_in[2];
    const float* beta  = (const float*)d_in[3];
    float* out = (float*)d_out;
    float* ws  = (float*)d_ws;

    float* stats   = ws;                        // 256 floats
    float* sigma_s = ws + 256;                  // NB*OC*OH*OW floats
    float* wrpk    = sigma_s + (size_t)NB * OC * OH * OW;

    hipMemsetAsync(stats, 0, 256 * sizeof(float), stream);

    repack_w<<<(CIN * OC * 16 + 255) / 256, 256, 0, stream>>>(cw, wrpk);

    dim3 gA(2 * (W / TS), H / TS, NB);   // halves adjacent in x for L2 sharing
    conv_kernel<<<gA, 256, 0, stream>>>(x, wrpk, sigma_s, stats);

    bn_kernel<<<1, 64, 0, stream>>>(gamma, beta, stats);

    dim3 gC(OH, NB * 4);
    out_kernel<<<gC, 256, 0, stream>>>(x, sigma_s, stats, out);
}

// Round 5
// 115.437 us; speedup vs baseline: 4.3123x; 1.7743x over previous
//
#include <hip/hip_runtime.h>

typedef short bf16x8 __attribute__((ext_vector_type(8)));
typedef float f32x16 __attribute__((ext_vector_type(16)));

#define CIN 64
#define OC 18
#define NB 4
#define H 256
#define W 256
#define HW (H * W)
#define OH 128
#define OW 128
#define EPS 1e-5f

#define TS 16
#define HALO 18
#define NPOS (HALO * HALO)    // 324

// ws layout (floats):
//   [0..17] sum  [18..35] sumsq  [36..53] scale  [54..71] shift
//   [256 ...]  sigma_s [NB][OC][OH][OW]  (1,179,648 floats)
//   then       wB: MFMA-fragment-ordered bf16 weights, 36 steps x 64 lanes x uint4

__device__ __forceinline__ int refl(int i, int n) {
    if (i < 0) i = -i;
    if (i >= n) i = 2 * n - 2 - i;
    return i;
}

__device__ __forceinline__ unsigned pack_bf16(float a, float b) {
    __bf16 lo = (__bf16)a, hi = (__bf16)b;
    return (unsigned)__builtin_bit_cast(unsigned short, lo) |
           ((unsigned)__builtin_bit_cast(unsigned short, hi) << 16);
}

// ---------------------------------------------------------------------------
// repack weights into B-fragment order for mfma_f32_32x32x16_bf16.
// step s (0..35): tap = s>>2, ci0 = (s&3)*16. lane l: oc = l&31, kg = l>>5.
// element j (0..7): ci = ci0 + kg*8 + j. value = w[oc][ci][tap] (0 if oc>=18).
// ---------------------------------------------------------------------------
__global__ void repack_w(const float* __restrict__ wgt, uint4* __restrict__ wB)
{
    int idx = blockIdx.x * 256 + threadIdx.x;    // s*64 + l
    if (idx >= 36 * 64) return;
    int s = idx >> 6, l = idx & 63;
    int tap = s >> 2, ci0 = (s & 3) * 16;
    int oc = l & 31, kg = l >> 5;
    unsigned r[4];
#pragma unroll
    for (int jp = 0; jp < 4; jp++) {
        float v0 = 0.f, v1 = 0.f;
        int ci = ci0 + kg * 8 + jp * 2;
        if (oc < OC) {
            v0 = wgt[(oc * CIN + ci) * 9 + tap];
            v1 = wgt[(oc * CIN + ci + 1) * 9 + tap];
        }
        r[jp] = pack_bf16(v0, v1);
    }
    wB[idx] = make_uint4(r[0], r[1], r[2], r[3]);
}

// ---------------------------------------------------------------------------
// Kernel A: implicit-GEMM bf16 MFMA conv + fused BN-stats + strided sigma.
// Block = 16x16 px tile, 256 thr / 4 waves. LDS: halo channel-last bf16,
// word(pos, i=ci>>1) = pos*32 + (((i>>2) ^ pos) & 7)*4 + (i&3)  (XOR swizzle).
// Wave w computes strips {w, w+4}; strip t = pixel rows {2t, 2t+1} x 16 cols.
// D (32x32): col = lane&31 = oc, row = (reg&3)+8*(reg>>2)+4*(lane>>5) = pixel.
// ---------------------------------------------------------------------------
__global__ __launch_bounds__(256) void conv_kernel(
        const float* __restrict__ x, const uint4* __restrict__ wB,
        float* __restrict__ sigma_s, float* __restrict__ stats)
{
    __shared__ unsigned xt[NPOS * 32];   // 41472 B
    __shared__ float sred[2 * OC];

    const int tid = threadIdx.x;
    const int h0 = blockIdx.y * TS, w0 = blockIdx.x * TS;
    const int n = blockIdx.z;

    if (tid < 2 * OC) sred[tid] = 0.f;

    // ---- staging: pos0 = tid, pos1 = tid+256 ----
    int g0, g1 = 0;
    {
        int r = tid / HALO, c = tid - r * HALO;
        g0 = refl(h0 + r - 1, H) * W + refl(w0 + c - 1, W);
    }
    const bool v1 = (tid + 256) < NPOS;
    if (v1) {
        int i = tid + 256, r = i / HALO, c = i - r * HALO;
        g1 = refl(h0 + r - 1, H) * W + refl(w0 + c - 1, W);
    }
    const float* xn = x + (size_t)n * CIN * HW;

#pragma unroll 4
    for (int i = 0; i < 32; i++) {     // i = ci>>1
        const float* xp = xn + (size_t)(2 * i) * HW;
        float a0 = xp[g0];
        float a1 = xp[g0 + HW];
        unsigned sw = (((unsigned)(i >> 2) ^ (unsigned)tid) & 7u) * 4u + (i & 3);
        xt[tid * 32 + sw] = pack_bf16(a0, a1);
        if (v1) {
            float b0 = xp[g1];
            float b1 = xp[g1 + HW];
            unsigned sw1 = (((unsigned)(i >> 2) ^ (unsigned)(tid + 256)) & 7u) * 4u + (i & 3);
            xt[(tid + 256) * 32 + sw1] = pack_bf16(b0, b1);
        }
    }
    __syncthreads();

    // ---- MFMA phase ----
    const int lane = tid & 63;
    const int wv = tid >> 6;
    const int m = lane & 31;            // pixel-in-strip (M index)
    const int kg = lane >> 5;           // k-group
    const int pr = m >> 4, pc = m & 15;
    const int t0 = wv, t1 = wv + 4;

    f32x16 acc0 = {};
    f32x16 acc1 = {};

    const int rbase0 = 2 * t0 + pr;     // tile row of this lane's pixel, strip 0
    const int rbase1 = 2 * t1 + pr;

#pragma unroll 1
    for (int kh = 0; kh < 3; kh++) {
#pragma unroll
        for (int kw = 0; kw < 3; kw++) {
#pragma unroll
            for (int q = 0; q < 4; q++) {
                const int s = (kh * 3 + kw) * 4 + q;
                uint4 bf = wB[s * 64 + lane];
                const int blk = q * 2 + kg;
                const int pos0 = (rbase0 + kh) * HALO + pc + kw;
                const int pos1 = (rbase1 + kh) * HALO + pc + kw;
                uint4 af0 = *(const uint4*)&xt[pos0 * 32 + (((blk ^ pos0) & 7) << 2)];
                uint4 af1 = *(const uint4*)&xt[pos1 * 32 + (((blk ^ pos1) & 7) << 2)];
                acc0 = __builtin_amdgcn_mfma_f32_32x32x16_bf16(
                        __builtin_bit_cast(bf16x8, af0), __builtin_bit_cast(bf16x8, bf), acc0, 0, 0, 0);
                acc1 = __builtin_amdgcn_mfma_f32_32x32x16_bf16(
                        __builtin_bit_cast(bf16x8, af1), __builtin_bit_cast(bf16x8, bf), acc1, 0, 0, 0);
            }
        }
    }

    // ---- fused BN stats ----
    float s = 0.f, ss = 0.f;
#pragma unroll
    for (int r = 0; r < 16; r++) {
        s  += acc0[r] + acc1[r];
        ss += acc0[r] * acc0[r] + acc1[r] * acc1[r];
    }
    s  += __shfl_xor(s, 32);
    ss += __shfl_xor(ss, 32);
    const int oc = m;                   // D col = lane&31
    if (kg == 0 && oc < OC) {
        atomicAdd(&sred[oc], s);
        atomicAdd(&sred[OC + oc], ss);
    }

    // ---- strided sigma store: even rows (p<16, pr=0 -> row 2t) & even cols ----
    if (oc < OC) {
        const int oy0 = h0 >> 1, ox0 = w0 >> 1;
        const size_t pbase = ((size_t)(n * OC + oc) * OH) * OW;
#pragma unroll
        for (int r = 0; r < 16; r++) {
            int p = (r & 3) + 8 * (r >> 2) + 4 * kg;
            if (p < 16 && (p & 1) == 0) {
                int ox = ox0 + (p >> 1);
                sigma_s[pbase + (size_t)(oy0 + t0) * OW + ox] = acc0[r];
                sigma_s[pbase + (size_t)(oy0 + t1) * OW + ox] = acc1[r];
            }
        }
    }

    __syncthreads();
    if (tid < 2 * OC) atomicAdd(&stats[tid], sred[tid]);
}

// ---------------------------------------------------------------------------
// Kernel B: finalize BN -> scale/shift
// ---------------------------------------------------------------------------
__global__ void bn_kernel(const float* __restrict__ gamma,
                          const float* __restrict__ beta,
                          float* __restrict__ stats)
{
    int t = threadIdx.x;
    if (t < OC) {
        float cnt = (float)NB * H * W;
        float mean = stats[t] / cnt;
        float var  = stats[18 + t] / cnt - mean * mean;
        float sc   = gamma[t] * rsqrtf(var + EPS);
        stats[36 + t] = sc;
        stats[54 + t] = beta[t] - mean * sc;
    }
}

// ---------------------------------------------------------------------------
// Kernel C: BN-affine + softmax(18) + 9-tap adaptive aggregation
// ---------------------------------------------------------------------------
__global__ __launch_bounds__(256) void out_kernel(
        const float* __restrict__ x, const float* __restrict__ sigma_s,
        const float* __restrict__ stats, float* __restrict__ out)
{
    __shared__ float p_lds[OC][OW];   // 9 KB

    const int oh = blockIdx.x;
    const int n  = blockIdx.y >> 2;
    const int c0 = (blockIdx.y & 3) * 16;
    const int h  = 2 * oh;
    const int tid = threadIdx.x;

    for (int i = tid; i < OC * OW; i += 256) {
        int chn = i >> 7, ow = i & 127;
        float v = sigma_s[((size_t)(n * OC + chn) * OH + oh) * OW + ow];
        p_lds[chn][ow] = v * stats[36 + chn] + stats[54 + chn];
    }
    __syncthreads();

    if (tid < OW) {
        int ow = tid;
        float m = -1e30f;
#pragma unroll
        for (int chn = 0; chn < OC; chn++) m = fmaxf(m, p_lds[chn][ow]);
        float e[OC], sum = 0.f;
#pragma unroll
        for (int chn = 0; chn < OC; chn++) { e[chn] = __expf(p_lds[chn][ow] - m); sum += e[chn]; }
        float inv = 1.f / sum;
#pragma unroll
        for (int chn = 0; chn < OC; chn++) p_lds[chn][ow] = e[chn] * inv;
    }
    __syncthreads();

    const int ow = tid & 127, cl = tid >> 7;
    for (int it = 0; it < 8; it++) {
        int c = c0 + it * 2 + cl;
        int g = c >> 5;
        const float* xb = x + (size_t)(n * CIN + c) * H * W;
        float a = 0.f;
#pragma unroll
        for (int kh = 0; kh < 3; kh++) {
            int ih = refl(h - 1 + kh, H);
#pragma unroll
            for (int kw = 0; kw < 3; kw++) {
                int iw = refl(2 * ow - 1 + kw, W);
                a = fmaf(xb[ih * W + iw], p_lds[g * 9 + kh * 3 + kw][ow], a);
            }
        }
        out[((size_t)(n * CIN + c) * OH + oh) * OW + ow] = a;
    }
}

// ---------------------------------------------------------------------------
extern "C" void kernel_launch(void* const* d_in, const int* in_sizes, int n_in,
                              void* d_out, int out_size, void* d_ws, size_t ws_size,
                              hipStream_t stream) {
    const float* x     = (const float*)d_in[0];
    const float* cw    = (const float*)d_in[1];
    const float* gamma = (const float*)d_in[2];
    const float* beta  = (const float*)d_in[3];
    float* out = (float*)d_out;
    float* ws  = (float*)d_ws;

    float* stats   = ws;                        // 256 floats
    float* sigma_s = ws + 256;                  // NB*OC*OH*OW floats
    uint4* wBp     = (uint4*)(sigma_s + (size_t)NB * OC * OH * OW);  // 36*64 uint4

    hipMemsetAsync(stats, 0, 256 * sizeof(float), stream);

    repack_w<<<(36 * 64 + 255) / 256, 256, 0, stream>>>(cw, wBp);

    dim3 gA(W / TS, H / TS, NB);
    conv_kernel<<<gA, 256, 0, stream>>>(x, wBp, sigma_s, stats);

    bn_kernel<<<1, 64, 0, stream>>>(gamma, beta, stats);

    dim3 gC(OH, NB * 4);
    out_kernel<<<gC, 256, 0, stream>>>(x, sigma_s, stats, out);
}

// Round 6
// 98.956 us; speedup vs baseline: 5.0305x; 1.1666x over previous
//
#include <hip/hip_runtime.h>

typedef short bf16x8 __attribute__((ext_vector_type(8)));
typedef float f32x16 __attribute__((ext_vector_type(16)));

#define CIN 64
#define OC 18
#define NB 4
#define H 256
#define W 256
#define HW (H * W)
#define OH 128
#define OW 128
#define EPS 1e-5f

#define TS 16
#define HALO 18

// ws layout (floats):
//   [0..17] sum  [18..35] sumsq  [36..53] scale  [54..71] shift
//   [256 ...]            sigma_s [NB][OC][OH][OW]   (1,179,648 floats)
//   sigma_s + 1179648 :  wB  (36*64 uint4 = 9,216 floats)
//   wB + 9216 floats  :  x_t NHWC bf16 [NB][H][W][CIN] (33.5 MB, 2,097,152 uint4)

__device__ __forceinline__ int refl(int i, int n) {
    if (i < 0) i = -i;
    if (i >= n) i = 2 * n - 2 - i;
    return i;
}

__device__ __forceinline__ unsigned pack_bf16(float a, float b) {
    __bf16 lo = (__bf16)a, hi = (__bf16)b;
    return (unsigned)__builtin_bit_cast(unsigned short, lo) |
           ((unsigned)__builtin_bit_cast(unsigned short, hi) << 16);
}

// ---------------------------------------------------------------------------
// repack weights into B-fragment order for mfma_f32_32x32x16_bf16.
// step s (0..35): tap = s>>2, ci0 = (s&3)*16. lane l: oc = l&31, kg = l>>5.
// element j: ci = ci0 + kg*8 + j. value = w[oc][ci][tap] (0 if oc>=18).
// ---------------------------------------------------------------------------
__global__ void repack_w(const float* __restrict__ wgt, uint4* __restrict__ wB)
{
    int idx = blockIdx.x * 256 + threadIdx.x;
    if (idx >= 36 * 64) return;
    int s = idx >> 6, l = idx & 63;
    int tap = s >> 2, ci0 = (s & 3) * 16;
    int oc = l & 31, kg = l >> 5;
    unsigned r[4];
#pragma unroll
    for (int jp = 0; jp < 4; jp++) {
        float v0 = 0.f, v1 = 0.f;
        int ci = ci0 + kg * 8 + jp * 2;
        if (oc < OC) {
            v0 = wgt[(oc * CIN + ci) * 9 + tap];
            v1 = wgt[(oc * CIN + ci + 1) * 9 + tap];
        }
        r[jp] = pack_bf16(v0, v1);
    }
    wB[idx] = make_uint4(r[0], r[1], r[2], r[3]);
}

// ---------------------------------------------------------------------------
// NCHW fp32 -> NHWC bf16 transpose. Block = one (n,h) row (256 px x 64 ch).
// LDS word (px, w) stored at px*32 + (w ^ (SWZ(px)<<2)), SWZ = (px>>2)&7.
// Read: float4 along W per channel; write: b128 per 8-channel group, coalesced.
// ---------------------------------------------------------------------------
__global__ __launch_bounds__(256) void nhwc_kernel(
        const float* __restrict__ x, uint4* __restrict__ xt)
{
    __shared__ uint4 bufq[2048];          // 32 KB
    unsigned* buf = (unsigned*)bufq;

    const int h = blockIdx.x, n = blockIdx.y;
    const int t = threadIdx.x;
    const int tpx = t & 63;               // float4 index along row
    const int cg = t >> 6;                // wave -> channel-quad group
    const int px0 = tpx * 4;
    const unsigned swz = ((unsigned)tpx & 7u) << 2;   // SWZ(px)= (px>>2)&7, px=4tpx+i

    const float* xrow = x + ((size_t)n * CIN * H + h) * W;

#pragma unroll
    for (int ii = 0; ii < 4; ii++) {
        const int cq = cg * 4 + ii;       // channel quad: channels 4cq..4cq+3
        const float4 A0 = *(const float4*)(xrow + (size_t)(4 * cq + 0) * HW + px0);
        const float4 A1 = *(const float4*)(xrow + (size_t)(4 * cq + 1) * HW + px0);
        const float4 A2 = *(const float4*)(xrow + (size_t)(4 * cq + 2) * HW + px0);
        const float4 A3 = *(const float4*)(xrow + (size_t)(4 * cq + 3) * HW + px0);
        const float a0[4] = {A0.x, A0.y, A0.z, A0.w};
        const float a1[4] = {A1.x, A1.y, A1.z, A1.w};
        const float a2[4] = {A2.x, A2.y, A2.z, A2.w};
        const float a3[4] = {A3.x, A3.y, A3.z, A3.w};
#pragma unroll
        for (int i = 0; i < 4; i++) {
            unsigned lo = pack_bf16(a0[i], a1[i]);
            unsigned hi = pack_bf16(a2[i], a3[i]);
            unsigned widx = (unsigned)(px0 + i) * 32u + ((unsigned)(2 * cq) ^ swz);
            *(uint2*)&buf[widx] = make_uint2(lo, hi);
        }
    }
    __syncthreads();

    const size_t rowbase = ((size_t)(n * H + h)) * W * 8;   // uint4 units
#pragma unroll
    for (int i = 0; i < 8; i++) {
        int flat = i * 256 + t;           // 0..2047
        int px = flat >> 3, j = flat & 7;
        unsigned sw = (((unsigned)px >> 2) & 7u) << 2;
        uint4 v = *(const uint4*)&buf[(unsigned)px * 32u + (((unsigned)(4 * j)) ^ sw)];
        xt[rowbase + flat] = v;
    }
}

// ---------------------------------------------------------------------------
// Kernel A: implicit-GEMM bf16 MFMA conv from NHWC bf16, NO LDS staging,
// no barriers in main loop. 16x16 px tile, 4 waves, wave -> strips {wv, wv+4}.
// A-frag = direct global dwordx4 (L2-resident). Fused BN stats + strided sigma.
// D (32x32): col = lane&31 = oc, row = (reg&3)+8*(reg>>2)+4*(lane>>5) = pixel.
// ---------------------------------------------------------------------------
__global__ __launch_bounds__(256) void conv_kernel(
        const uint4* __restrict__ xt, const uint4* __restrict__ wB,
        float* __restrict__ sigma_s, float* __restrict__ stats)
{
    __shared__ float sred[2 * OC];

    const int tid = threadIdx.x;
    const int h0 = blockIdx.y * TS, w0 = blockIdx.x * TS;
    const int n = blockIdx.z;

    if (tid < 2 * OC) sred[tid] = 0.f;
    __syncthreads();

    const int lane = tid & 63;
    const int wv = tid >> 6;
    const int m = lane & 31;
    const int kg = lane >> 5;
    const int pr = m >> 4, pc = m & 15;
    const int r0 = 2 * wv + pr;           // tile row, strip 0 (0..7)
    const int r1 = r0 + 8;                // strip 1 (8..15)

    // per-lane precomputed row/col offsets (uint4 units)
    size_t rown0[3], rown1[3];
    int colq[3];
#pragma unroll
    for (int kh = 0; kh < 3; kh++) {
        rown0[kh] = ((size_t)(n * H + refl(h0 + r0 + kh - 1, H))) * W * 8;
        rown1[kh] = ((size_t)(n * H + refl(h0 + r1 + kh - 1, H))) * W * 8;
    }
#pragma unroll
    for (int kw = 0; kw < 3; kw++)
        colq[kw] = refl(w0 + pc + kw - 1, W) * 8 + kg;

    f32x16 acc0 = {};
    f32x16 acc1 = {};

#pragma unroll 1
    for (int kh = 0; kh < 3; kh++) {
        const size_t ro0 = rown0[kh], ro1 = rown1[kh];
#pragma unroll
        for (int kw = 0; kw < 3; kw++) {
            const int cq = colq[kw];
#pragma unroll
            for (int q = 0; q < 4; q++) {
                const int s = (kh * 3 + kw) * 4 + q;
                uint4 bf = wB[s * 64 + lane];
                uint4 af0 = xt[ro0 + cq + q * 2];
                uint4 af1 = xt[ro1 + cq + q * 2];
                acc0 = __builtin_amdgcn_mfma_f32_32x32x16_bf16(
                        __builtin_bit_cast(bf16x8, af0), __builtin_bit_cast(bf16x8, bf), acc0, 0, 0, 0);
                acc1 = __builtin_amdgcn_mfma_f32_32x32x16_bf16(
                        __builtin_bit_cast(bf16x8, af1), __builtin_bit_cast(bf16x8, bf), acc1, 0, 0, 0);
            }
        }
    }

    // fused BN stats
    float s = 0.f, ss = 0.f;
#pragma unroll
    for (int r = 0; r < 16; r++) {
        s  += acc0[r] + acc1[r];
        ss += acc0[r] * acc0[r] + acc1[r] * acc1[r];
    }
    s  += __shfl_xor(s, 32);
    ss += __shfl_xor(ss, 32);
    const int oc = m;
    if (kg == 0 && oc < OC) {
        atomicAdd(&sred[oc], s);
        atomicAdd(&sred[OC + oc], ss);
    }

    // strided sigma store (even rows: strip row 2t -> p<16 & even cols)
    if (oc < OC) {
        const int oy0 = h0 >> 1, ox0 = w0 >> 1;
        const size_t pbase = ((size_t)(n * OC + oc) * OH) * OW;
#pragma unroll
        for (int r = 0; r < 16; r++) {
            int p = (r & 3) + 8 * (r >> 2) + 4 * kg;
            if (p < 16 && (p & 1) == 0) {
                int ox = ox0 + (p >> 1);
                sigma_s[pbase + (size_t)(oy0 + wv) * OW + ox] = acc0[r];
                sigma_s[pbase + (size_t)(oy0 + wv + 4) * OW + ox] = acc1[r];
            }
        }
    }

    __syncthreads();
    if (tid < 2 * OC) atomicAdd(&stats[tid], sred[tid]);
}

// ---------------------------------------------------------------------------
// Kernel B: finalize BN -> scale/shift
// ---------------------------------------------------------------------------
__global__ void bn_kernel(const float* __restrict__ gamma,
                          const float* __restrict__ beta,
                          float* __restrict__ stats)
{
    int t = threadIdx.x;
    if (t < OC) {
        float cnt = (float)NB * H * W;
        float mean = stats[t] / cnt;
        float var  = stats[18 + t] / cnt - mean * mean;
        float sc   = gamma[t] * rsqrtf(var + EPS);
        stats[36 + t] = sc;
        stats[54 + t] = beta[t] - mean * sc;
    }
}

// ---------------------------------------------------------------------------
// Kernel C: BN-affine + softmax(18) + 9-tap aggregation from NHWC bf16.
// Block = (oh, n, 64-ow half); thread item = (ow, 8-channel octet).
// ---------------------------------------------------------------------------
__global__ __launch_bounds__(256) void out_kernel(
        const uint4* __restrict__ xt, const float* __restrict__ sigma_s,
        const float* __restrict__ stats, float* __restrict__ out)
{
    __shared__ float p_lds[OC][64];

    const int oh = blockIdx.x;
    const int n  = blockIdx.y >> 1;
    const int ow0 = (blockIdx.y & 1) * 64;
    const int h  = 2 * oh;
    const int tid = threadIdx.x;

    for (int i = tid; i < OC * 64; i += 256) {
        int ch = i >> 6, owl = i & 63;
        float v = sigma_s[((size_t)(n * OC + ch) * OH + oh) * OW + ow0 + owl];
        p_lds[ch][owl] = v * stats[36 + ch] + stats[54 + ch];
    }
    __syncthreads();

    if (tid < 64) {
        int owl = tid;
        float mx = -1e30f;
#pragma unroll
        for (int ch = 0; ch < OC; ch++) mx = fmaxf(mx, p_lds[ch][owl]);
        float e[OC], sum = 0.f;
#pragma unroll
        for (int ch = 0; ch < OC; ch++) { e[ch] = __expf(p_lds[ch][owl] - mx); sum += e[ch]; }
        float inv = 1.f / sum;
#pragma unroll
        for (int ch = 0; ch < OC; ch++) p_lds[ch][owl] = e[ch] * inv;
    }
    __syncthreads();

    // precomputed reflected rows (block-uniform)
    int ihs[3];
#pragma unroll
    for (int kh = 0; kh < 3; kh++) ihs[kh] = refl(h - 1 + kh, H);

#pragma unroll
    for (int it = 0; it < 2; it++) {
        const int flat = it * 256 + tid;      // 0..511
        const int c8 = flat & 7;              // channel octet
        const int owl = flat >> 3;            // 0..63
        const int ow = ow0 + owl;
        const int g = (c8 >= 4) ? 1 : 0;

        float a[8];
#pragma unroll
        for (int j = 0; j < 8; j++) a[j] = 0.f;

#pragma unroll
        for (int kh = 0; kh < 3; kh++) {
            const size_t rb = ((size_t)(n * H + ihs[kh])) * W * 8;
#pragma unroll
            for (int kw = 0; kw < 3; kw++) {
                const int iw = refl(2 * ow - 1 + kw, W);
                const float p = p_lds[g * 9 + kh * 3 + kw][owl];
                uint4 v = xt[rb + (size_t)iw * 8 + c8];
                const unsigned uu[4] = {v.x, v.y, v.z, v.w};
#pragma unroll
                for (int q = 0; q < 4; q++) {
                    float lo = __builtin_bit_cast(float, uu[q] << 16);
                    float hi = __builtin_bit_cast(float, uu[q] & 0xffff0000u);
                    a[2 * q]     = fmaf(p, lo, a[2 * q]);
                    a[2 * q + 1] = fmaf(p, hi, a[2 * q + 1]);
                }
            }
        }

        const size_t ob = ((size_t)(n * CIN + c8 * 8) * OH + oh) * OW + ow;
#pragma unroll
        for (int j = 0; j < 8; j++)
            out[ob + (size_t)j * OH * OW] = a[j];
    }
}

// ---------------------------------------------------------------------------
extern "C" void kernel_launch(void* const* d_in, const int* in_sizes, int n_in,
                              void* d_out, int out_size, void* d_ws, size_t ws_size,
                              hipStream_t stream) {
    const float* x     = (const float*)d_in[0];
    const float* cw    = (const float*)d_in[1];
    const float* gamma = (const float*)d_in[2];
    const float* beta  = (const float*)d_in[3];
    float* out = (float*)d_out;
    float* ws  = (float*)d_ws;

    float* stats   = ws;                                    // 256 floats
    float* sigma_s = ws + 256;                              // 1,179,648 floats
    uint4* wBp     = (uint4*)(sigma_s + (size_t)NB * OC * OH * OW);   // 2304 uint4
    uint4* xtp     = wBp + 36 * 64;                         // 2,097,152 uint4 (33.5 MB)

    hipMemsetAsync(stats, 0, 256 * sizeof(float), stream);

    repack_w<<<(36 * 64 + 255) / 256, 256, 0, stream>>>(cw, wBp);

    dim3 gT(H, NB);
    nhwc_kernel<<<gT, 256, 0, stream>>>(x, xtp);

    dim3 gA(W / TS, H / TS, NB);
    conv_kernel<<<gA, 256, 0, stream>>>(xtp, wBp, sigma_s, stats);

    bn_kernel<<<1, 64, 0, stream>>>(gamma, beta, stats);

    dim3 gC(OH, NB * 2);
    out_kernel<<<gC, 256, 0, stream>>>(xtp, sigma_s, stats, out);
}

// Round 7
// 97.354 us; speedup vs baseline: 5.1133x; 1.0165x over previous
//
#include <hip/hip_runtime.h>

typedef short bf16x8 __attribute__((ext_vector_type(8)));
typedef float f32x16 __attribute__((ext_vector_type(16)));

#define CIN 64
#define OC 18
#define NB 4
#define H 256
#define W 256
#define HW (H * W)
#define OH 128
#define OW 128
#define EPS 1e-5f

#define TSX 16          // conv tile cols
#define TSY 8           // conv tile rows (1 strip of 2 rows per wave, 4 waves)

// ws layout (floats):
//   [0..17] sum  [18..35] sumsq  [36..53] scale  [54..71] shift
//   [256 ...]            sigma_s [NB][OC][OH][OW]   (1,179,648 floats)
//   sigma_s + 1179648 :  wB  (36*64 uint4 = 9,216 floats)
//   wB + 9216 floats  :  x_t NHWC bf16 [NB][H][W][CIN] (33.5 MB, 2,097,152 uint4)

__device__ __forceinline__ int refl(int i, int n) {
    if (i < 0) i = -i;
    if (i >= n) i = 2 * n - 2 - i;
    return i;
}

__device__ __forceinline__ unsigned pack_bf16(float a, float b) {
    __bf16 lo = (__bf16)a, hi = (__bf16)b;
    return (unsigned)__builtin_bit_cast(unsigned short, lo) |
           ((unsigned)__builtin_bit_cast(unsigned short, hi) << 16);
}

// ---------------------------------------------------------------------------
// repack weights into B-fragment order for mfma_f32_32x32x16_bf16.
// step s (0..35): tap = s>>2, ci0 = (s&3)*16. lane l: oc = l&31, kg = l>>5.
// element j: ci = ci0 + kg*8 + j. value = w[oc][ci][tap] (0 if oc>=18).
// ---------------------------------------------------------------------------
__global__ void repack_w(const float* __restrict__ wgt, uint4* __restrict__ wB)
{
    int idx = blockIdx.x * 256 + threadIdx.x;
    if (idx >= 36 * 64) return;
    int s = idx >> 6, l = idx & 63;
    int tap = s >> 2, ci0 = (s & 3) * 16;
    int oc = l & 31, kg = l >> 5;
    unsigned r[4];
#pragma unroll
    for (int jp = 0; jp < 4; jp++) {
        float v0 = 0.f, v1 = 0.f;
        int ci = ci0 + kg * 8 + jp * 2;
        if (oc < OC) {
            v0 = wgt[(oc * CIN + ci) * 9 + tap];
            v1 = wgt[(oc * CIN + ci + 1) * 9 + tap];
        }
        r[jp] = pack_bf16(v0, v1);
    }
    wB[idx] = make_uint4(r[0], r[1], r[2], r[3]);
}

// ---------------------------------------------------------------------------
// NCHW fp32 -> NHWC bf16 transpose. Block = one (n,h) row (256 px x 64 ch).
// ---------------------------------------------------------------------------
__global__ __launch_bounds__(256) void nhwc_kernel(
        const float* __restrict__ x, uint4* __restrict__ xt)
{
    __shared__ uint4 bufq[2048];          // 32 KB
    unsigned* buf = (unsigned*)bufq;

    const int h = blockIdx.x, n = blockIdx.y;
    const int t = threadIdx.x;
    const int tpx = t & 63;
    const int cg = t >> 6;
    const int px0 = tpx * 4;
    const unsigned swz = ((unsigned)tpx & 7u) << 2;

    const float* xrow = x + ((size_t)n * CIN * H + h) * W;

#pragma unroll
    for (int ii = 0; ii < 4; ii++) {
        const int cq = cg * 4 + ii;
        const float4 A0 = *(const float4*)(xrow + (size_t)(4 * cq + 0) * HW + px0);
        const float4 A1 = *(const float4*)(xrow + (size_t)(4 * cq + 1) * HW + px0);
        const float4 A2 = *(const float4*)(xrow + (size_t)(4 * cq + 2) * HW + px0);
        const float4 A3 = *(const float4*)(xrow + (size_t)(4 * cq + 3) * HW + px0);
        const float a0[4] = {A0.x, A0.y, A0.z, A0.w};
        const float a1[4] = {A1.x, A1.y, A1.z, A1.w};
        const float a2[4] = {A2.x, A2.y, A2.z, A2.w};
        const float a3[4] = {A3.x, A3.y, A3.z, A3.w};
#pragma unroll
        for (int i = 0; i < 4; i++) {
            unsigned lo = pack_bf16(a0[i], a1[i]);
            unsigned hi = pack_bf16(a2[i], a3[i]);
            unsigned widx = (unsigned)(px0 + i) * 32u + ((unsigned)(2 * cq) ^ swz);
            *(uint2*)&buf[widx] = make_uint2(lo, hi);
        }
    }
    __syncthreads();

    const size_t rowbase = ((size_t)(n * H + h)) * W * 8;
#pragma unroll
    for (int i = 0; i < 8; i++) {
        int flat = i * 256 + t;
        int px = flat >> 3, j = flat & 7;
        unsigned sw = (((unsigned)px >> 2) & 7u) << 2;
        uint4 v = *(const uint4*)&buf[(unsigned)px * 32u + (((unsigned)(4 * j)) ^ sw)];
        xt[rowbase + flat] = v;
    }
}

// ---------------------------------------------------------------------------
// Kernel A: implicit-GEMM bf16 MFMA conv from NHWC bf16.
// Block = 16x8 px tile, 4 waves, ONE 2-row strip per wave. Fully unrolled
// 36-step K loop (loads hoisted by compiler), no LDS staging, no barriers.
// D (32x32): col = lane&31 = oc, row = (reg&3)+8*(reg>>2)+4*(lane>>5) = pixel.
// ---------------------------------------------------------------------------
__global__ __launch_bounds__(256, 4) void conv_kernel(
        const uint4* __restrict__ xt, const uint4* __restrict__ wB,
        float* __restrict__ sigma_s, float* __restrict__ stats)
{
    __shared__ float sred[2 * OC];

    const int tid = threadIdx.x;
    const int h0 = blockIdx.y * TSY, w0 = blockIdx.x * TSX;
    const int n = blockIdx.z;

    if (tid < 2 * OC) sred[tid] = 0.f;
    __syncthreads();

    const int lane = tid & 63;
    const int wv = tid >> 6;
    const int m = lane & 31;
    const int kg = lane >> 5;
    const int pr = m >> 4, pc = m & 15;
    const int r0 = 2 * wv + pr;           // this lane's tile row (0..8)

    size_t rown[3];
    int colq[3];
#pragma unroll
    for (int kh = 0; kh < 3; kh++)
        rown[kh] = ((size_t)(n * H + refl(h0 + r0 + kh - 1, H))) * W * 8;
#pragma unroll
    for (int kw = 0; kw < 3; kw++)
        colq[kw] = refl(w0 + pc + kw - 1, W) * 8 + kg;

    f32x16 acc = {};

#pragma unroll
    for (int kh = 0; kh < 3; kh++) {
        const size_t ro = rown[kh];
#pragma unroll
        for (int kw = 0; kw < 3; kw++) {
            const int cq = colq[kw];
#pragma unroll
            for (int q = 0; q < 4; q++) {
                const int s = (kh * 3 + kw) * 4 + q;
                uint4 bf = wB[s * 64 + lane];
                uint4 af = xt[ro + cq + q * 2];
                acc = __builtin_amdgcn_mfma_f32_32x32x16_bf16(
                        __builtin_bit_cast(bf16x8, af), __builtin_bit_cast(bf16x8, bf), acc, 0, 0, 0);
            }
        }
    }

    // fused BN stats (wave strip = 32 pixels; combine kg halves via xor-32)
    float s = 0.f, ss = 0.f;
#pragma unroll
    for (int r = 0; r < 16; r++) {
        s  += acc[r];
        ss += acc[r] * acc[r];
    }
    s  += __shfl_xor(s, 32);
    ss += __shfl_xor(ss, 32);
    const int oc = m;
    if (kg == 0 && oc < OC) {
        atomicAdd(&sred[oc], s);
        atomicAdd(&sred[OC + oc], ss);
    }

    // strided sigma store: even tile-rows are p<16 (strip row 0); even cols
    if (oc < OC) {
        const int oy = (h0 >> 1) + wv;
        const int ox0 = w0 >> 1;
        const size_t pbase = ((size_t)(n * OC + oc) * OH + oy) * OW;
#pragma unroll
        for (int r = 0; r < 16; r++) {
            int p = (r & 3) + 8 * (r >> 2) + 4 * kg;
            if (p < 16 && (p & 1) == 0)
                sigma_s[pbase + ox0 + (p >> 1)] = acc[r];
        }
    }

    __syncthreads();
    if (tid < 2 * OC) atomicAdd(&stats[tid], sred[tid]);
}

// ---------------------------------------------------------------------------
// Kernel B: finalize BN -> scale/shift
// ---------------------------------------------------------------------------
__global__ void bn_kernel(const float* __restrict__ gamma,
                          const float* __restrict__ beta,
                          float* __restrict__ stats)
{
    int t = threadIdx.x;
    if (t < OC) {
        float cnt = (float)NB * H * W;
        float mean = stats[t] / cnt;
        float var  = stats[18 + t] / cnt - mean * mean;
        float sc   = gamma[t] * rsqrtf(var + EPS);
        stats[36 + t] = sc;
        stats[54 + t] = beta[t] - mean * sc;
    }
}

// ---------------------------------------------------------------------------
// Kernel C: BN-affine + softmax(18) + 9-tap aggregation from NHWC bf16.
// ---------------------------------------------------------------------------
__global__ __launch_bounds__(256) void out_kernel(
        const uint4* __restrict__ xt, const float* __restrict__ sigma_s,
        const float* __restrict__ stats, float* __restrict__ out)
{
    __shared__ float p_lds[OC][64];

    const int oh = blockIdx.x;
    const int n  = blockIdx.y >> 1;
    const int ow0 = (blockIdx.y & 1) * 64;
    const int h  = 2 * oh;
    const int tid = threadIdx.x;

    for (int i = tid; i < OC * 64; i += 256) {
        int ch = i >> 6, owl = i & 63;
        float v = sigma_s[((size_t)(n * OC + ch) * OH + oh) * OW + ow0 + owl];
        p_lds[ch][owl] = v * stats[36 + ch] + stats[54 + ch];
    }
    __syncthreads();

    if (tid < 64) {
        int owl = tid;
        float mx = -1e30f;
#pragma unroll
        for (int ch = 0; ch < OC; ch++) mx = fmaxf(mx, p_lds[ch][owl]);
        float e[OC], sum = 0.f;
#pragma unroll
        for (int ch = 0; ch < OC; ch++) { e[ch] = __expf(p_lds[ch][owl] - mx); sum += e[ch]; }
        float inv = 1.f / sum;
#pragma unroll
        for (int ch = 0; ch < OC; ch++) p_lds[ch][owl] = e[ch] * inv;
    }
    __syncthreads();

    int ihs[3];
#pragma unroll
    for (int kh = 0; kh < 3; kh++) ihs[kh] = refl(h - 1 + kh, H);

#pragma unroll
    for (int it = 0; it < 2; it++) {
        const int flat = it * 256 + tid;
        const int c8 = flat & 7;
        const int owl = flat >> 3;
        const int ow = ow0 + owl;
        const int g = (c8 >= 4) ? 1 : 0;

        float a[8];
#pragma unroll
        for (int j = 0; j < 8; j++) a[j] = 0.f;

#pragma unroll
        for (int kh = 0; kh < 3; kh++) {
            const size_t rb = ((size_t)(n * H + ihs[kh])) * W * 8;
#pragma unroll
            for (int kw = 0; kw < 3; kw++) {
                const int iw = refl(2 * ow - 1 + kw, W);
                const float p = p_lds[g * 9 + kh * 3 + kw][owl];
                uint4 v = xt[rb + (size_t)iw * 8 + c8];
                const unsigned uu[4] = {v.x, v.y, v.z, v.w};
#pragma unroll
                for (int q = 0; q < 4; q++) {
                    float lo = __builtin_bit_cast(float, uu[q] << 16);
                    float hi = __builtin_bit_cast(float, uu[q] & 0xffff0000u);
                    a[2 * q]     = fmaf(p, lo, a[2 * q]);
                    a[2 * q + 1] = fmaf(p, hi, a[2 * q + 1]);
                }
            }
        }

        const size_t ob = ((size_t)(n * CIN + c8 * 8) * OH + oh) * OW + ow;
#pragma unroll
        for (int j = 0; j < 8; j++)
            out[ob + (size_t)j * OH * OW] = a[j];
    }
}

// ---------------------------------------------------------------------------
extern "C" void kernel_launch(void* const* d_in, const int* in_sizes, int n_in,
                              void* d_out, int out_size, void* d_ws, size_t ws_size,
                              hipStream_t stream) {
    const float* x     = (const float*)d_in[0];
    const float* cw    = (const float*)d_in[1];
    const float* gamma = (const float*)d_in[2];
    const float* beta  = (const float*)d_in[3];
    float* out = (float*)d_out;
    float* ws  = (float*)d_ws;

    float* stats   = ws;                                    // 256 floats
    float* sigma_s = ws + 256;                              // 1,179,648 floats
    uint4* wBp     = (uint4*)(sigma_s + (size_t)NB * OC * OH * OW);   // 2304 uint4
    uint4* xtp     = wBp + 36 * 64;                         // 2,097,152 uint4 (33.5 MB)

    hipMemsetAsync(stats, 0, 256 * sizeof(float), stream);

    repack_w<<<(36 * 64 + 255) / 256, 256, 0, stream>>>(cw, wBp);

    dim3 gT(H, NB);
    nhwc_kernel<<<gT, 256, 0, stream>>>(x, xtp);

    dim3 gA(W / TSX, H / TSY, NB);   // 16 x 32 x 4 = 2048 blocks
    conv_kernel<<<gA, 256, 0, stream>>>(xtp, wBp, sigma_s, stats);

    bn_kernel<<<1, 64, 0, stream>>>(gamma, beta, stats);

    dim3 gC(OH, NB * 2);
    out_kernel<<<gC, 256, 0, stream>>>(xtp, sigma_s, stats, out);
}

// Round 8
// 97.272 us; speedup vs baseline: 5.1176x; 1.0008x over previous
//
#include <hip/hip_runtime.h>

typedef short bf16x8 __attribute__((ext_vector_type(8)));
typedef float f32x16 __attribute__((ext_vector_type(16)));

#define CIN 64
#define OC 18
#define NB 4
#define H 256
#define W 256
#define HW (H * W)
#define OH 128
#define OW 128
#define EPS 1e-5f

#define TSX 16          // conv tile cols
#define TSY 8           // conv tile rows (1 strip of 2 rows per wave, 4 waves)

// ws layout (floats):
//   [0..17] sum  [18..35] sumsq  [36..53] scale  [54..71] shift
//   [256 ...]            sigma_s [NB][OC][OH][OW]   (1,179,648 floats)
//   sigma_s + 1179648 :  wB  (36*64 uint4 = 9,216 floats)
//   wB + 9216 floats  :  x_t NHWC bf16 [NB][H][W][CIN] (33.5 MB, 2,097,152 uint4)

__device__ __forceinline__ int refl(int i, int n) {
    if (i < 0) i = -i;
    if (i >= n) i = 2 * n - 2 - i;
    return i;
}

__device__ __forceinline__ unsigned pack_bf16(float a, float b) {
    __bf16 lo = (__bf16)a, hi = (__bf16)b;
    return (unsigned)__builtin_bit_cast(unsigned short, lo) |
           ((unsigned)__builtin_bit_cast(unsigned short, hi) << 16);
}

// ---------------------------------------------------------------------------
// repack weights into B-fragment order for mfma_f32_32x32x16_bf16.
// step s (0..35): tap = s>>2, ci0 = (s&3)*16. lane l: oc = l&31, kg = l>>5.
// element j: ci = ci0 + kg*8 + j. value = w[oc][ci][tap] (0 if oc>=18).
// ---------------------------------------------------------------------------
__global__ void repack_w(const float* __restrict__ wgt, uint4* __restrict__ wB)
{
    int idx = blockIdx.x * 256 + threadIdx.x;
    if (idx >= 36 * 64) return;
    int s = idx >> 6, l = idx & 63;
    int tap = s >> 2, ci0 = (s & 3) * 16;
    int oc = l & 31, kg = l >> 5;
    unsigned r[4];
#pragma unroll
    for (int jp = 0; jp < 4; jp++) {
        float v0 = 0.f, v1 = 0.f;
        int ci = ci0 + kg * 8 + jp * 2;
        if (oc < OC) {
            v0 = wgt[(oc * CIN + ci) * 9 + tap];
            v1 = wgt[(oc * CIN + ci + 1) * 9 + tap];
        }
        r[jp] = pack_bf16(v0, v1);
    }
    wB[idx] = make_uint4(r[0], r[1], r[2], r[3]);
}

// ---------------------------------------------------------------------------
// NCHW fp32 -> NHWC bf16 transpose. Block = one (n,h) row (256 px x 64 ch).
// ---------------------------------------------------------------------------
__global__ __launch_bounds__(256) void nhwc_kernel(
        const float* __restrict__ x, uint4* __restrict__ xt)
{
    __shared__ uint4 bufq[2048];          // 32 KB
    unsigned* buf = (unsigned*)bufq;

    const int h = blockIdx.x, n = blockIdx.y;
    const int t = threadIdx.x;
    const int tpx = t & 63;
    const int cg = t >> 6;
    const int px0 = tpx * 4;
    const unsigned swz = ((unsigned)tpx & 7u) << 2;

    const float* xrow = x + ((size_t)n * CIN * H + h) * W;

#pragma unroll
    for (int ii = 0; ii < 4; ii++) {
        const int cq = cg * 4 + ii;
        const float4 A0 = *(const float4*)(xrow + (size_t)(4 * cq + 0) * HW + px0);
        const float4 A1 = *(const float4*)(xrow + (size_t)(4 * cq + 1) * HW + px0);
        const float4 A2 = *(const float4*)(xrow + (size_t)(4 * cq + 2) * HW + px0);
        const float4 A3 = *(const float4*)(xrow + (size_t)(4 * cq + 3) * HW + px0);
        const float a0[4] = {A0.x, A0.y, A0.z, A0.w};
        const float a1[4] = {A1.x, A1.y, A1.z, A1.w};
        const float a2[4] = {A2.x, A2.y, A2.z, A2.w};
        const float a3[4] = {A3.x, A3.y, A3.z, A3.w};
#pragma unroll
        for (int i = 0; i < 4; i++) {
            unsigned lo = pack_bf16(a0[i], a1[i]);
            unsigned hi = pack_bf16(a2[i], a3[i]);
            unsigned widx = (unsigned)(px0 + i) * 32u + ((unsigned)(2 * cq) ^ swz);
            *(uint2*)&buf[widx] = make_uint2(lo, hi);
        }
    }
    __syncthreads();

    const size_t rowbase = ((size_t)(n * H + h)) * W * 8;
#pragma unroll
    for (int i = 0; i < 8; i++) {
        int flat = i * 256 + t;
        int px = flat >> 3, j = flat & 7;
        unsigned sw = (((unsigned)px >> 2) & 7u) << 2;
        uint4 v = *(const uint4*)&buf[(unsigned)px * 32u + (((unsigned)(4 * j)) ^ sw)];
        xt[rowbase + flat] = v;
    }
}

// ---------------------------------------------------------------------------
// Kernel A: implicit-GEMM bf16 MFMA conv from NHWC bf16.
// Block = 16x8 px tile, 4 waves, ONE 2-row strip per wave.
// B-fragments staged in LDS (36 KB, once per block, shared by all 4 waves).
// A: explicit 3-deep 4-buffer register prefetch (static indices only).
// 1-D grid, XCD-pinned decode: wgid%8 <-> h-stripe, so all 16 w-tiles of a
// stripe (sharing 10 xt rows) land on one XCD's L2.
// D (32x32): col = lane&31 = oc, row = (reg&3)+8*(reg>>2)+4*(lane>>5) = pixel.
// ---------------------------------------------------------------------------
__global__ __launch_bounds__(256, 4) void conv_kernel(
        const uint4* __restrict__ xt, const uint4* __restrict__ wB,
        float* __restrict__ sigma_s, float* __restrict__ stats)
{
    __shared__ uint4 wlds[36 * 64];     // 36,864 B
    __shared__ float sred[2 * OC];

    const int tid = threadIdx.x;

    // XCD-pinned work decode (wgid % 8 is the XCD class under round-robin)
    const int b = blockIdx.x;
    const int n = b >> 9;               // 512 blocks per n
    const int r = b & 511;
    const int cls = r & 7;
    const int k = r >> 3;               // 0..63
    const int wt = k & 15;
    const int hq = k >> 4;              // 0..3
    const int h0 = (hq * 8 + cls) * TSY;
    const int w0 = wt * TSX;

    if (tid < 2 * OC) sred[tid] = 0.f;

    // stage B fragments to LDS
#pragma unroll
    for (int i = 0; i < 9; i++) wlds[i * 256 + tid] = wB[i * 256 + tid];
    __syncthreads();

    const int lane = tid & 63;
    const int wv = tid >> 6;
    const int m = lane & 31;
    const int kg = lane >> 5;
    const int pr = m >> 4, pc = m & 15;
    const int r0 = 2 * wv + pr;           // this lane's tile row (0..8)

    size_t rown[3];
    int colq[3];
#pragma unroll
    for (int kh = 0; kh < 3; kh++)
        rown[kh] = ((size_t)(n * H + refl(h0 + r0 + kh - 1, H))) * W * 8;
#pragma unroll
    for (int kw = 0; kw < 3; kw++)
        colq[kw] = refl(w0 + pc + kw - 1, W) * 8 + kg;

    f32x16 acc = {};
    uint4 pf[4][4];                       // 4 buffers x 4 q-frags (static idx)

    // prologue: issue groups 0..2 (group g = (kh,kw) = (g/3, g%3))
#pragma unroll
    for (int g = 0; g < 3; g++) {
#pragma unroll
        for (int q = 0; q < 4; q++)
            pf[g][q] = xt[rown[0] + colq[g] + q * 2];
    }

#pragma unroll
    for (int g = 0; g < 9; g++) {
        // issue group g+3 before consuming group g (keeps ~12 loads in flight)
        if (g + 3 < 9) {
            const int g3 = g + 3;
            const int kh3 = g3 / 3, kw3 = g3 % 3;
#pragma unroll
            for (int q = 0; q < 4; q++)
                pf[g3 & 3][q] = xt[rown[kh3] + colq[kw3] + q * 2];
        }
#pragma unroll
        for (int q = 0; q < 4; q++) {
            uint4 bf = wlds[(g * 4 + q) * 64 + lane];
            acc = __builtin_amdgcn_mfma_f32_32x32x16_bf16(
                    __builtin_bit_cast(bf16x8, pf[g & 3][q]),
                    __builtin_bit_cast(bf16x8, bf), acc, 0, 0, 0);
        }
    }

    // fused BN stats (wave strip = 32 pixels; combine kg halves via xor-32)
    float s = 0.f, ss = 0.f;
#pragma unroll
    for (int rr = 0; rr < 16; rr++) {
        s  += acc[rr];
        ss += acc[rr] * acc[rr];
    }
    s  += __shfl_xor(s, 32);
    ss += __shfl_xor(ss, 32);
    const int oc = m;
    if (kg == 0 && oc < OC) {
        atomicAdd(&sred[oc], s);
        atomicAdd(&sred[OC + oc], ss);
    }

    // strided sigma store: even tile-rows are p<16 (strip row 0); even cols
    if (oc < OC) {
        const int oy = (h0 >> 1) + wv;
        const int ox0 = w0 >> 1;
        const size_t pbase = ((size_t)(n * OC + oc) * OH + oy) * OW;
#pragma unroll
        for (int rr = 0; rr < 16; rr++) {
            int p = (rr & 3) + 8 * (rr >> 2) + 4 * kg;
            if (p < 16 && (p & 1) == 0)
                sigma_s[pbase + ox0 + (p >> 1)] = acc[rr];
        }
    }

    __syncthreads();
    if (tid < 2 * OC) atomicAdd(&stats[tid], sred[tid]);
}

// ---------------------------------------------------------------------------
// Kernel B: finalize BN -> scale/shift
// ---------------------------------------------------------------------------
__global__ void bn_kernel(const float* __restrict__ gamma,
                          const float* __restrict__ beta,
                          float* __restrict__ stats)
{
    int t = threadIdx.x;
    if (t < OC) {
        float cnt = (float)NB * H * W;
        float mean = stats[t] / cnt;
        float var  = stats[18 + t] / cnt - mean * mean;
        float sc   = gamma[t] * rsqrtf(var + EPS);
        stats[36 + t] = sc;
        stats[54 + t] = beta[t] - mean * sc;
    }
}

// ---------------------------------------------------------------------------
// Kernel C: BN-affine + softmax(18) + 9-tap aggregation from NHWC bf16.
// ---------------------------------------------------------------------------
__global__ __launch_bounds__(256) void out_kernel(
        const uint4* __restrict__ xt, const float* __restrict__ sigma_s,
        const float* __restrict__ stats, float* __restrict__ out)
{
    __shared__ float p_lds[OC][64];

    const int oh = blockIdx.x;
    const int n  = blockIdx.y >> 1;
    const int ow0 = (blockIdx.y & 1) * 64;
    const int h  = 2 * oh;
    const int tid = threadIdx.x;

    for (int i = tid; i < OC * 64; i += 256) {
        int ch = i >> 6, owl = i & 63;
        float v = sigma_s[((size_t)(n * OC + ch) * OH + oh) * OW + ow0 + owl];
        p_lds[ch][owl] = v * stats[36 + ch] + stats[54 + ch];
    }
    __syncthreads();

    if (tid < 64) {
        int owl = tid;
        float mx = -1e30f;
#pragma unroll
        for (int ch = 0; ch < OC; ch++) mx = fmaxf(mx, p_lds[ch][owl]);
        float e[OC], sum = 0.f;
#pragma unroll
        for (int ch = 0; ch < OC; ch++) { e[ch] = __expf(p_lds[ch][owl] - mx); sum += e[ch]; }
        float inv = 1.f / sum;
#pragma unroll
        for (int ch = 0; ch < OC; ch++) p_lds[ch][owl] = e[ch] * inv;
    }
    __syncthreads();

    int ihs[3];
#pragma unroll
    for (int kh = 0; kh < 3; kh++) ihs[kh] = refl(h - 1 + kh, H);

#pragma unroll
    for (int it = 0; it < 2; it++) {
        const int flat = it * 256 + tid;
        const int c8 = flat & 7;
        const int owl = flat >> 3;
        const int ow = ow0 + owl;
        const int g = (c8 >= 4) ? 1 : 0;

        float a[8];
#pragma unroll
        for (int j = 0; j < 8; j++) a[j] = 0.f;

#pragma unroll
        for (int kh = 0; kh < 3; kh++) {
            const size_t rb = ((size_t)(n * H + ihs[kh])) * W * 8;
#pragma unroll
            for (int kw = 0; kw < 3; kw++) {
                const int iw = refl(2 * ow - 1 + kw, W);
                const float p = p_lds[g * 9 + kh * 3 + kw][owl];
                uint4 v = xt[rb + (size_t)iw * 8 + c8];
                const unsigned uu[4] = {v.x, v.y, v.z, v.w};
#pragma unroll
                for (int q = 0; q < 4; q++) {
                    float lo = __builtin_bit_cast(float, uu[q] << 16);
                    float hi = __builtin_bit_cast(float, uu[q] & 0xffff0000u);
                    a[2 * q]     = fmaf(p, lo, a[2 * q]);
                    a[2 * q + 1] = fmaf(p, hi, a[2 * q + 1]);
                }
            }
        }

        const size_t ob = ((size_t)(n * CIN + c8 * 8) * OH + oh) * OW + ow;
#pragma unroll
        for (int j = 0; j < 8; j++)
            out[ob + (size_t)j * OH * OW] = a[j];
    }
}

// ---------------------------------------------------------------------------
extern "C" void kernel_launch(void* const* d_in, const int* in_sizes, int n_in,
                              void* d_out, int out_size, void* d_ws, size_t ws_size,
                              hipStream_t stream) {
    const float* x     = (const float*)d_in[0];
    const float* cw    = (const float*)d_in[1];
    const float* gamma = (const float*)d_in[2];
    const float* beta  = (const float*)d_in[3];
    float* out = (float*)d_out;
    float* ws  = (float*)d_ws;

    float* stats   = ws;                                    // 256 floats
    float* sigma_s = ws + 256;                              // 1,179,648 floats
    uint4* wBp     = (uint4*)(sigma_s + (size_t)NB * OC * OH * OW);   // 2304 uint4
    uint4* xtp     = wBp + 36 * 64;                         // 2,097,152 uint4 (33.5 MB)

    hipMemsetAsync(stats, 0, 256 * sizeof(float), stream);

    repack_w<<<(36 * 64 + 255) / 256, 256, 0, stream>>>(cw, wBp);

    dim3 gT(H, NB);
    nhwc_kernel<<<gT, 256, 0, stream>>>(x, xtp);

    conv_kernel<<<dim3(NB * 512), 256, 0, stream>>>(xtp, wBp, sigma_s, stats);

    bn_kernel<<<1, 64, 0, stream>>>(gamma, beta, stats);

    dim3 gC(OH, NB * 2);
    out_kernel<<<gC, 256, 0, stream>>>(xtp, sigma_s, stats, out);
}

// Round 9
// 86.386 us; speedup vs baseline: 5.7625x; 1.1260x over previous
//
#include <hip/hip_runtime.h>

typedef short bf16x8 __attribute__((ext_vector_type(8)));
typedef float f32x16 __attribute__((ext_vector_type(16)));

#define CIN 64
#define OC 18
#define NB 4
#define H 256
#define W 256
#define HW (H * W)
#define OH 128
#define OW 128
#define EPS 1e-5f

#define TSX 16          // conv tile cols
#define TSY 8           // conv tile rows (1 strip of 2 rows per wave, 4 waves)
#define WPX 36          // LDS words per pixel (8 uint4 = 32 words, padded to 36)
#define ROWW (18 * WPX) // 648 words per halo row
#define AWORDS (10 * ROWW)  // 6480 words = 25.9 KB

// ws layout (floats):
//   [0..17] sum  [18..35] sumsq  [36..53] scale  [54..71] shift
//   [256 ...]            sigma_s [NB][OC][OH][OW]   (1,179,648 floats)
//   sigma_s + 1179648 :  wB  (36*64 uint4 = 9,216 floats)
//   wB + 9216 floats  :  x_t NHWC bf16 [NB][H][W][CIN] (33.5 MB, 2,097,152 uint4)

__device__ __forceinline__ int refl(int i, int n) {
    if (i < 0) i = -i;
    if (i >= n) i = 2 * n - 2 - i;
    return i;
}

__device__ __forceinline__ unsigned pack_bf16(float a, float b) {
    __bf16 lo = (__bf16)a, hi = (__bf16)b;
    return (unsigned)__builtin_bit_cast(unsigned short, lo) |
           ((unsigned)__builtin_bit_cast(unsigned short, hi) << 16);
}

// ---------------------------------------------------------------------------
// repack weights into B-fragment order for mfma_f32_32x32x16_bf16.
// step s (0..35): tap = s>>2, ci0 = (s&3)*16. lane l: oc = l&31, kg = l>>5.
// element j: ci = ci0 + kg*8 + j. value = w[oc][ci][tap] (0 if oc>=18).
// ---------------------------------------------------------------------------
__global__ void repack_w(const float* __restrict__ wgt, uint4* __restrict__ wB)
{
    int idx = blockIdx.x * 256 + threadIdx.x;
    if (idx >= 36 * 64) return;
    int s = idx >> 6, l = idx & 63;
    int tap = s >> 2, ci0 = (s & 3) * 16;
    int oc = l & 31, kg = l >> 5;
    unsigned r[4];
#pragma unroll
    for (int jp = 0; jp < 4; jp++) {
        float v0 = 0.f, v1 = 0.f;
        int ci = ci0 + kg * 8 + jp * 2;
        if (oc < OC) {
            v0 = wgt[(oc * CIN + ci) * 9 + tap];
            v1 = wgt[(oc * CIN + ci + 1) * 9 + tap];
        }
        r[jp] = pack_bf16(v0, v1);
    }
    wB[idx] = make_uint4(r[0], r[1], r[2], r[3]);
}

// ---------------------------------------------------------------------------
// NCHW fp32 -> NHWC bf16 transpose. Block = one (n,h) row (256 px x 64 ch).
// ---------------------------------------------------------------------------
__global__ __launch_bounds__(256) void nhwc_kernel(
        const float* __restrict__ x, uint4* __restrict__ xt)
{
    __shared__ uint4 bufq[2048];          // 32 KB
    unsigned* buf = (unsigned*)bufq;

    const int h = blockIdx.x, n = blockIdx.y;
    const int t = threadIdx.x;
    const int tpx = t & 63;
    const int cg = t >> 6;
    const int px0 = tpx * 4;
    const unsigned swz = ((unsigned)tpx & 7u) << 2;

    const float* xrow = x + ((size_t)n * CIN * H + h) * W;

#pragma unroll
    for (int ii = 0; ii < 4; ii++) {
        const int cq = cg * 4 + ii;
        const float4 A0 = *(const float4*)(xrow + (size_t)(4 * cq + 0) * HW + px0);
        const float4 A1 = *(const float4*)(xrow + (size_t)(4 * cq + 1) * HW + px0);
        const float4 A2 = *(const float4*)(xrow + (size_t)(4 * cq + 2) * HW + px0);
        const float4 A3 = *(const float4*)(xrow + (size_t)(4 * cq + 3) * HW + px0);
        const float a0[4] = {A0.x, A0.y, A0.z, A0.w};
        const float a1[4] = {A1.x, A1.y, A1.z, A1.w};
        const float a2[4] = {A2.x, A2.y, A2.z, A2.w};
        const float a3[4] = {A3.x, A3.y, A3.z, A3.w};
#pragma unroll
        for (int i = 0; i < 4; i++) {
            unsigned lo = pack_bf16(a0[i], a1[i]);
            unsigned hi = pack_bf16(a2[i], a3[i]);
            unsigned widx = (unsigned)(px0 + i) * 32u + ((unsigned)(2 * cq) ^ swz);
            *(uint2*)&buf[widx] = make_uint2(lo, hi);
        }
    }
    __syncthreads();

    const size_t rowbase = ((size_t)(n * H + h)) * W * 8;
#pragma unroll
    for (int i = 0; i < 8; i++) {
        int flat = i * 256 + t;
        int px = flat >> 3, j = flat & 7;
        unsigned sw = (((unsigned)px >> 2) & 7u) << 2;
        uint4 v = *(const uint4*)&buf[(unsigned)px * 32u + (((unsigned)(4 * j)) ^ sw)];
        xt[rowbase + flat] = v;
    }
}

// ---------------------------------------------------------------------------
// Kernel A: implicit-GEMM bf16 MFMA conv. A-halo AND B-fragments staged in
// LDS; inner loop is pure ds_read_b128 + MFMA (no global ops, no barriers).
// Block = 16x8 px tile, 4 waves, 1 strip/wave. Staging issued as an explicit
// load-batch -> write-batch so all 15 global loads are in flight together.
// XCD decode: class = (n, h-half) -> 4.3 MB working set per XCD (~L2).
// D (32x32): col = lane&31 = oc, row = (reg&3)+8*(reg>>2)+4*(lane>>5) = pixel.
// ---------------------------------------------------------------------------
__global__ __launch_bounds__(256) void conv_kernel(
        const uint4* __restrict__ xt, const uint4* __restrict__ wB,
        float* __restrict__ sigma_s, float* __restrict__ stats)
{
    __shared__ unsigned alds[AWORDS];   // 25,920 B  (A halo, padded)
    __shared__ uint4 wlds[36 * 64];     // 36,864 B  (B fragments)
    __shared__ float sred[2 * OC];

    const int tid = threadIdx.x;

    // XCD-pinned decode: wgid%8 = XCD class; class = (n, h-half)
    const int b = blockIdx.x;
    const int cls = b & 7;
    const int idx = b >> 3;             // 0..255
    const int n = cls >> 1;
    const int hhalf = cls & 1;
    const int ht = idx >> 4;            // 0..15
    const int wt = idx & 15;
    const int h0 = (hhalf * 16 + ht) * TSY;
    const int w0 = wt * TSX;

    if (tid < 2 * OC) sred[tid] = 0.f;

    // ---- staging: batch-issue 6 A loads + 9 B loads, then 15 ds_writes ----
    uint4 ast[6];
    int   alw[6];
#pragma unroll
    for (int i = 0; i < 6; i++) {
        int e = tid + i * 256;
        if (e > 1439) e = 1439;         // clamp: duplicate write, benign
        int row = e / 144;
        int rr  = e - row * 144;
        int px  = rr >> 3;
        int c16 = rr & 7;
        int gh = refl(h0 + row - 1, H);
        int gw = refl(w0 + px - 1, W);
        ast[i] = xt[((size_t)(n * H + gh) * W + gw) * 8 + c16];
        alw[i] = row * ROWW + px * WPX + c16 * 4;
    }
    uint4 wst[9];
#pragma unroll
    for (int i = 0; i < 9; i++) wst[i] = wB[i * 256 + tid];

#pragma unroll
    for (int i = 0; i < 6; i++) *(uint4*)&alds[alw[i]] = ast[i];
#pragma unroll
    for (int i = 0; i < 9; i++) wlds[i * 256 + tid] = wst[i];

    __syncthreads();

    // ---- MFMA phase: pure LDS ----
    const int lane = tid & 63;
    const int wv = tid >> 6;
    const int m = lane & 31;
    const int kg = lane >> 5;
    const int pr = m >> 4, pc = m & 15;
    const int r0 = 2 * wv + pr;         // lane's tile row (0..8)

    const int abase = r0 * ROWW + pc * WPX + kg * 4;   // + kh*ROWW + kw*WPX + q*8
    const unsigned* ap = &alds[abase];
    const uint4* wp = &wlds[lane];      // + s*64

    f32x16 acc = {};
#pragma unroll
    for (int g = 0; g < 9; g++) {
        const int kh = g / 3, kw = g % 3;
#pragma unroll
        for (int q = 0; q < 4; q++) {
            uint4 af = *(const uint4*)(ap + kh * ROWW + kw * WPX + q * 8);
            uint4 bf = wp[(g * 4 + q) * 64];
            acc = __builtin_amdgcn_mfma_f32_32x32x16_bf16(
                    __builtin_bit_cast(bf16x8, af),
                    __builtin_bit_cast(bf16x8, bf), acc, 0, 0, 0);
        }
    }

    // ---- fused BN stats ----
    float s = 0.f, ss = 0.f;
#pragma unroll
    for (int rr = 0; rr < 16; rr++) {
        s  += acc[rr];
        ss += acc[rr] * acc[rr];
    }
    s  += __shfl_xor(s, 32);
    ss += __shfl_xor(ss, 32);
    const int oc = m;
    if (kg == 0 && oc < OC) {
        atomicAdd(&sred[oc], s);
        atomicAdd(&sred[OC + oc], ss);
    }

    // ---- strided sigma store ----
    if (oc < OC) {
        const int oy = (h0 >> 1) + wv;
        const int ox0 = w0 >> 1;
        const size_t pbase = ((size_t)(n * OC + oc) * OH + oy) * OW;
#pragma unroll
        for (int rr = 0; rr < 16; rr++) {
            int p = (rr & 3) + 8 * (rr >> 2) + 4 * kg;
            if (p < 16 && (p & 1) == 0)
                sigma_s[pbase + ox0 + (p >> 1)] = acc[rr];
        }
    }

    __syncthreads();
    if (tid < 2 * OC) atomicAdd(&stats[tid], sred[tid]);
}

// ---------------------------------------------------------------------------
// Kernel B: finalize BN -> scale/shift
// ---------------------------------------------------------------------------
__global__ void bn_kernel(const float* __restrict__ gamma,
                          const float* __restrict__ beta,
                          float* __restrict__ stats)
{
    int t = threadIdx.x;
    if (t < OC) {
        float cnt = (float)NB * H * W;
        float mean = stats[t] / cnt;
        float var  = stats[18 + t] / cnt - mean * mean;
        float sc   = gamma[t] * rsqrtf(var + EPS);
        stats[36 + t] = sc;
        stats[54 + t] = beta[t] - mean * sc;
    }
}

// ---------------------------------------------------------------------------
// Kernel C: BN-affine + softmax(18) + 9-tap aggregation from NHWC bf16.
// ---------------------------------------------------------------------------
__global__ __launch_bounds__(256) void out_kernel(
        const uint4* __restrict__ xt, const float* __restrict__ sigma_s,
        const float* __restrict__ stats, float* __restrict__ out)
{
    __shared__ float p_lds[OC][64];

    const int oh = blockIdx.x;
    const int n  = blockIdx.y >> 1;
    const int ow0 = (blockIdx.y & 1) * 64;
    const int h  = 2 * oh;
    const int tid = threadIdx.x;

    for (int i = tid; i < OC * 64; i += 256) {
        int ch = i >> 6, owl = i & 63;
        float v = sigma_s[((size_t)(n * OC + ch) * OH + oh) * OW + ow0 + owl];
        p_lds[ch][owl] = v * stats[36 + ch] + stats[54 + ch];
    }
    __syncthreads();

    if (tid < 64) {
        int owl = tid;
        float mx = -1e30f;
#pragma unroll
        for (int ch = 0; ch < OC; ch++) mx = fmaxf(mx, p_lds[ch][owl]);
        float e[OC], sum = 0.f;
#pragma unroll
        for (int ch = 0; ch < OC; ch++) { e[ch] = __expf(p_lds[ch][owl] - mx); sum += e[ch]; }
        float inv = 1.f / sum;
#pragma unroll
        for (int ch = 0; ch < OC; ch++) p_lds[ch][owl] = e[ch] * inv;
    }
    __syncthreads();

    int ihs[3];
#pragma unroll
    for (int kh = 0; kh < 3; kh++) ihs[kh] = refl(h - 1 + kh, H);

#pragma unroll
    for (int it = 0; it < 2; it++) {
        const int flat = it * 256 + tid;
        const int c8 = flat & 7;
        const int owl = flat >> 3;
        const int ow = ow0 + owl;
        const int g = (c8 >= 4) ? 1 : 0;

        float a[8];
#pragma unroll
        for (int j = 0; j < 8; j++) a[j] = 0.f;

#pragma unroll
        for (int kh = 0; kh < 3; kh++) {
            const size_t rb = ((size_t)(n * H + ihs[kh])) * W * 8;
#pragma unroll
            for (int kw = 0; kw < 3; kw++) {
                const int iw = refl(2 * ow - 1 + kw, W);
                const float p = p_lds[g * 9 + kh * 3 + kw][owl];
                uint4 v = xt[rb + (size_t)iw * 8 + c8];
                const unsigned uu[4] = {v.x, v.y, v.z, v.w};
#pragma unroll
                for (int q = 0; q < 4; q++) {
                    float lo = __builtin_bit_cast(float, uu[q] << 16);
                    float hi = __builtin_bit_cast(float, uu[q] & 0xffff0000u);
                    a[2 * q]     = fmaf(p, lo, a[2 * q]);
                    a[2 * q + 1] = fmaf(p, hi, a[2 * q + 1]);
                }
            }
        }

        const size_t ob = ((size_t)(n * CIN + c8 * 8) * OH + oh) * OW + ow;
#pragma unroll
        for (int j = 0; j < 8; j++)
            out[ob + (size_t)j * OH * OW] = a[j];
    }
}

// ---------------------------------------------------------------------------
extern "C" void kernel_launch(void* const* d_in, const int* in_sizes, int n_in,
                              void* d_out, int out_size, void* d_ws, size_t ws_size,
                              hipStream_t stream) {
    const float* x     = (const float*)d_in[0];
    const float* cw    = (const float*)d_in[1];
    const float* gamma = (const float*)d_in[2];
    const float* beta  = (const float*)d_in[3];
    float* out = (float*)d_out;
    float* ws  = (float*)d_ws;

    float* stats   = ws;                                    // 256 floats
    float* sigma_s = ws + 256;                              // 1,179,648 floats
    uint4* wBp     = (uint4*)(sigma_s + (size_t)NB * OC * OH * OW);   // 2304 uint4
    uint4* xtp     = wBp + 36 * 64;                         // 2,097,152 uint4 (33.5 MB)

    hipMemsetAsync(stats, 0, 256 * sizeof(float), stream);

    repack_w<<<(36 * 64 + 255) / 256, 256, 0, stream>>>(cw, wBp);

    dim3 gT(H, NB);
    nhwc_kernel<<<gT, 256, 0, stream>>>(x, xtp);

    conv_kernel<<<dim3(NB * 512), 256, 0, stream>>>(xtp, wBp, sigma_s, stats);

    bn_kernel<<<1, 64, 0, stream>>>(gamma, beta, stats);

    dim3 gC(OH, NB * 2);
    out_kernel<<<gC, 256, 0, stream>>>(xtp, sigma_s, stats, out);
}

// Round 10
// 67.850 us; speedup vs baseline: 7.3367x; 1.2732x over previous
//
#include <hip/hip_runtime.h>

typedef short bf16x8 __attribute__((ext_vector_type(8)));
typedef float f32x16 __attribute__((ext_vector_type(16)));

#define CIN 64
#define OC 18
#define NB 4
#define H 256
#define W 256
#define HW (H * W)
#define OH 128
#define OW 128
#define EPS 1e-5f

#define TSX 16          // tile cols
#define TSY 8           // tile rows (1 strip of 2 rows per wave, 4 waves)
#define NTILE 4         // tiles per block (along W)
#define WPX 36          // LDS words per pixel (32 data + 4 pad)
#define ROWW (18 * WPX) // 648 words per halo row
#define AWORDS (10 * ROWW)  // 6480 words = 25.9 KB per buffer
#define NWB 512         // number of conv blocks

// ws layout (floats):
//   [0..255]   stats (36..53 scale, 54..71 shift)
//   [256 ...]  sigma_s [NB][OC][OH][OW]  (1,179,648 floats)
//   then       wB  (36*64 uint4)
//   then       x_t NHWC bf16 [NB][H][W][CIN]  (2,097,152 uint4)
//   then       part [36][NWB] floats (per-block BN partials)

__device__ __forceinline__ int refl(int i, int n) {
    if (i < 0) i = -i;
    if (i >= n) i = 2 * n - 2 - i;
    return i;
}

__device__ __forceinline__ unsigned pack_bf16(float a, float b) {
    __bf16 lo = (__bf16)a, hi = (__bf16)b;
    return (unsigned)__builtin_bit_cast(unsigned short, lo) |
           ((unsigned)__builtin_bit_cast(unsigned short, hi) << 16);
}

// ---------------------------------------------------------------------------
// repack weights into B-fragment order for mfma_f32_32x32x16_bf16.
// step s (0..35): tap = s>>2, ci0 = (s&3)*16. lane l: oc = l&31, kg = l>>5.
// element j: ci = ci0 + kg*8 + j. value = w[oc][ci][tap] (0 if oc>=18).
// ---------------------------------------------------------------------------
__global__ void repack_w(const float* __restrict__ wgt, uint4* __restrict__ wB)
{
    int idx = blockIdx.x * 256 + threadIdx.x;
    if (idx >= 36 * 64) return;
    int s = idx >> 6, l = idx & 63;
    int tap = s >> 2, ci0 = (s & 3) * 16;
    int oc = l & 31, kg = l >> 5;
    unsigned r[4];
#pragma unroll
    for (int jp = 0; jp < 4; jp++) {
        float v0 = 0.f, v1 = 0.f;
        int ci = ci0 + kg * 8 + jp * 2;
        if (oc < OC) {
            v0 = wgt[(oc * CIN + ci) * 9 + tap];
            v1 = wgt[(oc * CIN + ci + 1) * 9 + tap];
        }
        r[jp] = pack_bf16(v0, v1);
    }
    wB[idx] = make_uint4(r[0], r[1], r[2], r[3]);
}

// ---------------------------------------------------------------------------
// NCHW fp32 -> NHWC bf16 transpose. Block = one (n,h) row (256 px x 64 ch).
// ---------------------------------------------------------------------------
__global__ __launch_bounds__(256) void nhwc_kernel(
        const float* __restrict__ x, uint4* __restrict__ xt)
{
    __shared__ uint4 bufq[2048];          // 32 KB
    unsigned* buf = (unsigned*)bufq;

    const int h = blockIdx.x, n = blockIdx.y;
    const int t = threadIdx.x;
    const int tpx = t & 63;
    const int cg = t >> 6;
    const int px0 = tpx * 4;
    const unsigned swz = ((unsigned)tpx & 7u) << 2;

    const float* xrow = x + ((size_t)n * CIN * H + h) * W;

#pragma unroll
    for (int ii = 0; ii < 4; ii++) {
        const int cq = cg * 4 + ii;
        const float4 A0 = *(const float4*)(xrow + (size_t)(4 * cq + 0) * HW + px0);
        const float4 A1 = *(const float4*)(xrow + (size_t)(4 * cq + 1) * HW + px0);
        const float4 A2 = *(const float4*)(xrow + (size_t)(4 * cq + 2) * HW + px0);
        const float4 A3 = *(const float4*)(xrow + (size_t)(4 * cq + 3) * HW + px0);
        const float a0[4] = {A0.x, A0.y, A0.z, A0.w};
        const float a1[4] = {A1.x, A1.y, A1.z, A1.w};
        const float a2[4] = {A2.x, A2.y, A2.z, A2.w};
        const float a3[4] = {A3.x, A3.y, A3.z, A3.w};
#pragma unroll
        for (int i = 0; i < 4; i++) {
            unsigned lo = pack_bf16(a0[i], a1[i]);
            unsigned hi = pack_bf16(a2[i], a3[i]);
            unsigned widx = (unsigned)(px0 + i) * 32u + ((unsigned)(2 * cq) ^ swz);
            *(uint2*)&buf[widx] = make_uint2(lo, hi);
        }
    }
    __syncthreads();

    const size_t rowbase = ((size_t)(n * H + h)) * W * 8;
#pragma unroll
    for (int i = 0; i < 8; i++) {
        int flat = i * 256 + t;
        int px = flat >> 3, j = flat & 7;
        unsigned sw = (((unsigned)px >> 2) & 7u) << 2;
        uint4 v = *(const uint4*)&buf[(unsigned)px * 32u + (((unsigned)(4 * j)) ^ sw)];
        xt[rowbase + flat] = v;
    }
}

// ---------------------------------------------------------------------------
// Kernel A: persistent-tile implicit-GEMM bf16 MFMA conv.
// Block = 8 rows x 64 cols = 4 tiles of 16x8; A double-buffered in LDS,
// B compacted in LDS (staged once), 1 barrier per tile. No global atomics:
// per-block BN partials to part[36][NWB].
// XCD decode: cls = bid&7 = (n, h-half); per-XCD working set ~4.3 MB.
// D (32x32): col = lane&31 = oc, row = (reg&3)+8*(reg>>2)+4*(lane>>5) = pixel.
// ---------------------------------------------------------------------------
__global__ __launch_bounds__(256) void conv_kernel(
        const uint4* __restrict__ xt, const uint4* __restrict__ wB,
        float* __restrict__ sigma_s, float* __restrict__ part)
{
    __shared__ unsigned alds[2][AWORDS];   // 2 x 25,920 B
    __shared__ uint4 wlds[1344];           // compact B: 36 steps x 37 + pad
    __shared__ float sred[2 * OC];

    const int tid = threadIdx.x;

    // decode: cls = (n, hhalf); L -> (ht_local, wquad)
    const int b = blockIdx.x;
    const int cls = b & 7;
    const int L = b >> 3;                  // 0..63
    const int n = cls >> 1;
    const int hhalf = cls & 1;
    const int ht = L >> 2;                 // 0..15
    const int wq = L & 3;                  // 0..3
    const int h0 = (hhalf * 16 + ht) * TSY;
    const int w0 = wq * (NTILE * TSX);

    if (tid < 2 * OC) sred[tid] = 0.f;

    // ---- t-invariant A staging map (6 elements/thread) ----
    size_t gbase[6];
    int    alw[6], apx[6];
    bool   av[6];
#pragma unroll
    for (int i = 0; i < 6; i++) {
        int e = tid + i * 256;
        av[i] = e < 1440;
        if (!av[i]) e = 1439;
        int row = e / 144;
        int rr  = e - row * 144;
        int px  = rr >> 3;
        int c   = rr & 7;
        int gh  = refl(h0 + row - 1, H);
        gbase[i] = (size_t)(n * H + gh) * W * 8 + c;
        apx[i]  = px;
        alw[i]  = row * ROWW + px * WPX + c * 4;
    }

    // ---- stage B (compact) + A tile 0 ----
    {
        uint4 wst[6];
        bool  wv6[6];
        int   we[6];
#pragma unroll
        for (int i = 0; i < 6; i++) {
            int e = tid + i * 256;
            wv6[i] = e < 1332;
            we[i] = e;
            if (wv6[i]) {
                int s = e / 37, j = e - s * 37;
                uint4 v = make_uint4(0, 0, 0, 0);
                if (j < 36) {
                    int kgj = j / 18, ocj = j - kgj * 18;
                    v = wB[s * 64 + kgj * 32 + ocj];
                }
                wst[i] = v;
            }
        }
        uint4 ast[6];
#pragma unroll
        for (int i = 0; i < 6; i++) {
            if (av[i]) {
                int gw = refl(w0 + apx[i] - 1, W);
                ast[i] = xt[gbase[i] + (size_t)gw * 8];
            }
        }
#pragma unroll
        for (int i = 0; i < 6; i++)
            if (wv6[i]) wlds[we[i]] = wst[i];
#pragma unroll
        for (int i = 0; i < 6; i++)
            if (av[i]) *(uint4*)&alds[0][alw[i]] = ast[i];
    }
    __syncthreads();

    // ---- lane geometry ----
    const int lane = tid & 63;
    const int wv = tid >> 6;
    const int m = lane & 31;
    const int kg = lane >> 5;
    const int pr = m >> 4, pc = m & 15;
    const int r0 = 2 * wv + pr;
    const int abase = r0 * ROWW + pc * WPX + kg * 4;
    const int bidx = (m < OC) ? (kg * OC + m) : 36;   // compact B index (36 = zero slot)

    float s_acc = 0.f, ss_acc = 0.f;
    const int oy = (h0 >> 1) + wv;
    const size_t pb_n = (size_t)n * OC;

#pragma unroll 1
    for (int t = 0; t < NTILE; t++) {
        // issue next tile's A loads (held in regs across compute)
        uint4 pfa[6];
        if (t + 1 < NTILE) {
            const int w0n = w0 + (t + 1) * TSX;
#pragma unroll
            for (int i = 0; i < 6; i++) {
                if (av[i]) {
                    int gw = refl(w0n + apx[i] - 1, W);
                    pfa[i] = xt[gbase[i] + (size_t)gw * 8];
                }
            }
        }

        // compute tile t from alds[t&1]
        const unsigned* ap = &alds[t & 1][abase];
        f32x16 acc = {};
#pragma unroll
        for (int g = 0; g < 9; g++) {
            const int kh = g / 3, kw = g % 3;
#pragma unroll
            for (int q = 0; q < 4; q++) {
                uint4 af = *(const uint4*)(ap + kh * ROWW + kw * WPX + q * 8);
                uint4 bf = wlds[(g * 4 + q) * 37 + bidx];
                acc = __builtin_amdgcn_mfma_f32_32x32x16_bf16(
                        __builtin_bit_cast(bf16x8, af),
                        __builtin_bit_cast(bf16x8, bf), acc, 0, 0, 0);
            }
        }

        // stats accumulate + strided sigma store
#pragma unroll
        for (int rr = 0; rr < 16; rr++) {
            s_acc  += acc[rr];
            ss_acc += acc[rr] * acc[rr];
        }
        if (m < OC) {
            const int ox0 = (w0 + t * TSX) >> 1;
            const size_t pbase = ((pb_n + m) * OH + oy) * OW;
#pragma unroll
            for (int rr = 0; rr < 16; rr++) {
                int p = (rr & 3) + 8 * (rr >> 2) + 4 * kg;
                if (p < 16 && (p & 1) == 0)
                    sigma_s[pbase + ox0 + (p >> 1)] = acc[rr];
            }
        }

        __syncthreads();   // all waves done reading alds[t&1]

        if (t + 1 < NTILE) {
#pragma unroll
            for (int i = 0; i < 6; i++)
                if (av[i]) *(uint4*)&alds[(t + 1) & 1][alw[i]] = pfa[i];
            __syncthreads();
        }
    }

    // ---- BN partials: block-local reduce, one plain store per channel ----
    s_acc  += __shfl_xor(s_acc, 32);
    ss_acc += __shfl_xor(ss_acc, 32);
    if (kg == 0 && m < OC) {
        atomicAdd(&sred[m], s_acc);
        atomicAdd(&sred[OC + m], ss_acc);
    }
    __syncthreads();
    if (tid < 2 * OC) part[tid * NWB + blockIdx.x] = sred[tid];
}

// ---------------------------------------------------------------------------
// Kernel B: reduce per-block partials + finalize BN -> scale/shift.
// 18 blocks; block c reduces part[c][*] and part[18+c][*].
// ---------------------------------------------------------------------------
__global__ __launch_bounds__(256) void bn_kernel(
        const float* __restrict__ gamma, const float* __restrict__ beta,
        const float* __restrict__ part, float* __restrict__ stats)
{
    __shared__ float red[8];
    const int c = blockIdx.x;
    const int tid = threadIdx.x;

    float s  = part[c * NWB + tid]        + part[c * NWB + 256 + tid];
    float ss = part[(OC + c) * NWB + tid] + part[(OC + c) * NWB + 256 + tid];
#pragma unroll
    for (int off = 32; off > 0; off >>= 1) {
        s  += __shfl_down(s, off);
        ss += __shfl_down(ss, off);
    }
    const int wid = tid >> 6, lanez = tid & 63;
    if (lanez == 0) { red[wid] = s; red[4 + wid] = ss; }
    __syncthreads();
    if (tid == 0) {
        float S  = red[0] + red[1] + red[2] + red[3];
        float SS = red[4] + red[5] + red[6] + red[7];
        float cnt = (float)NB * H * W;
        float mean = S / cnt;
        float var  = SS / cnt - mean * mean;
        float sc   = gamma[c] * rsqrtf(var + EPS);
        stats[36 + c] = sc;
        stats[54 + c] = beta[c] - mean * sc;
    }
}

// ---------------------------------------------------------------------------
// Kernel C: BN-affine + softmax(18) + 9-tap aggregation from NHWC bf16.
// ---------------------------------------------------------------------------
__global__ __launch_bounds__(256) void out_kernel(
        const uint4* __restrict__ xt, const float* __restrict__ sigma_s,
        const float* __restrict__ stats, float* __restrict__ out)
{
    __shared__ float p_lds[OC][64];

    const int oh = blockIdx.x;
    const int n  = blockIdx.y >> 1;
    const int ow0 = (blockIdx.y & 1) * 64;
    const int h  = 2 * oh;
    const int tid = threadIdx.x;

    for (int i = tid; i < OC * 64; i += 256) {
        int ch = i >> 6, owl = i & 63;
        float v = sigma_s[((size_t)(n * OC + ch) * OH + oh) * OW + ow0 + owl];
        p_lds[ch][owl] = v * stats[36 + ch] + stats[54 + ch];
    }
    __syncthreads();

    if (tid < 64) {
        int owl = tid;
        float mx = -1e30f;
#pragma unroll
        for (int ch = 0; ch < OC; ch++) mx = fmaxf(mx, p_lds[ch][owl]);
        float e[OC], sum = 0.f;
#pragma unroll
        for (int ch = 0; ch < OC; ch++) { e[ch] = __expf(p_lds[ch][owl] - mx); sum += e[ch]; }
        float inv = 1.f / sum;
#pragma unroll
        for (int ch = 0; ch < OC; ch++) p_lds[ch][owl] = e[ch] * inv;
    }
    __syncthreads();

    int ihs[3];
#pragma unroll
    for (int kh = 0; kh < 3; kh++) ihs[kh] = refl(h - 1 + kh, H);

#pragma unroll
    for (int it = 0; it < 2; it++) {
        const int flat = it * 256 + tid;
        const int c8 = flat & 7;
        const int owl = flat >> 3;
        const int ow = ow0 + owl;
        const int g = (c8 >= 4) ? 1 : 0;

        float a[8];
#pragma unroll
        for (int j = 0; j < 8; j++) a[j] = 0.f;

#pragma unroll
        for (int kh = 0; kh < 3; kh++) {
            const size_t rb = ((size_t)(n * H + ihs[kh])) * W * 8;
#pragma unroll
            for (int kw = 0; kw < 3; kw++) {
                const int iw = refl(2 * ow - 1 + kw, W);
                const float p = p_lds[g * 9 + kh * 3 + kw][owl];
                uint4 v = xt[rb + (size_t)iw * 8 + c8];
                const unsigned uu[4] = {v.x, v.y, v.z, v.w};
#pragma unroll
                for (int q = 0; q < 4; q++) {
                    float lo = __builtin_bit_cast(float, uu[q] << 16);
                    float hi = __builtin_bit_cast(float, uu[q] & 0xffff0000u);
                    a[2 * q]     = fmaf(p, lo, a[2 * q]);
                    a[2 * q + 1] = fmaf(p, hi, a[2 * q + 1]);
                }
            }
        }

        const size_t ob = ((size_t)(n * CIN + c8 * 8) * OH + oh) * OW + ow;
#pragma unroll
        for (int j = 0; j < 8; j++)
            out[ob + (size_t)j * OH * OW] = a[j];
    }
}

// ---------------------------------------------------------------------------
extern "C" void kernel_launch(void* const* d_in, const int* in_sizes, int n_in,
                              void* d_out, int out_size, void* d_ws, size_t ws_size,
                              hipStream_t stream) {
    const float* x     = (const float*)d_in[0];
    const float* cw    = (const float*)d_in[1];
    const float* gamma = (const float*)d_in[2];
    const float* beta  = (const float*)d_in[3];
    float* out = (float*)d_out;
    float* ws  = (float*)d_ws;

    float* stats   = ws;                                    // 256 floats
    float* sigma_s = ws + 256;                              // 1,179,648 floats
    uint4* wBp     = (uint4*)(sigma_s + (size_t)NB * OC * OH * OW);   // 2304 uint4
    uint4* xtp     = wBp + 36 * 64;                         // 2,097,152 uint4
    float* part    = (float*)(xtp + (size_t)NB * H * W * 8);          // 36*512 floats

    repack_w<<<(36 * 64 + 255) / 256, 256, 0, stream>>>(cw, wBp);

    dim3 gT(H, NB);
    nhwc_kernel<<<gT, 256, 0, stream>>>(x, xtp);

    conv_kernel<<<dim3(NWB), 256, 0, stream>>>(xtp, wBp, sigma_s, part);

    bn_kernel<<<OC, 256, 0, stream>>>(gamma, beta, part, stats);

    dim3 gC(OH, NB * 2);
    out_kernel<<<gC, 256, 0, stream>>>(xtp, sigma_s, stats, out);
}

// Round 11
// 62.206 us; speedup vs baseline: 8.0025x; 1.0907x over previous
//
#include <hip/hip_runtime.h>

typedef short bf16x8 __attribute__((ext_vector_type(8)));
typedef float f32x16 __attribute__((ext_vector_type(16)));

#define CIN 64
#define OC 18
#define NB 4
#define H 256
#define W 256
#define HW (H * W)
#define OH 128
#define OW 128
#define EPS 1e-5f

#define TSX 16          // tile cols
#define TSY 8           // tile rows (1 strip of 2 rows per wave, 4 waves)
#define NTILE 4         // tiles per block (along W)
#define WPX 36          // LDS words per pixel (32 data + 4 pad)
#define ROWW (18 * WPX) // 648 words per halo row
#define AWORDS (10 * ROWW)  // 6480 words = 25.9 KB per buffer
#define NWB 512         // number of conv blocks

// ws layout (floats):
//   [0..255]   stats (36..53 scale, 54..71 shift)
//   [256 ...]  sigma_s [NB][OC][OH][OW]  (1,179,648 floats)
//   then       wB  (36*64 uint4)
//   then       x_t NHWC bf16 [NB][H][W][CIN]  (2,097,152 uint4)
//   then       part [36][NWB] floats (per-block BN partials)

__device__ __forceinline__ int refl(int i, int n) {
    if (i < 0) i = -i;
    if (i >= n) i = 2 * n - 2 - i;
    return i;
}

__device__ __forceinline__ unsigned pack_bf16(float a, float b) {
    __bf16 lo = (__bf16)a, hi = (__bf16)b;
    return (unsigned)__builtin_bit_cast(unsigned short, lo) |
           ((unsigned)__builtin_bit_cast(unsigned short, hi) << 16);
}

// ---------------------------------------------------------------------------
// NCHW fp32 -> NHWC bf16 transpose (+ fused weight repack on blockIdx.y==NB).
// repack: wgt[(oc*CIN+ci)*9+tap] -> wB[s*64+l], s=tap*4+(ci>>4),
//         l=(ci>>3 & 1)*32 + oc, elem j = ci%8.  Zeros for oc>=18.
// ---------------------------------------------------------------------------
__global__ __launch_bounds__(256) void nhwc_kernel(
        const float* __restrict__ x, uint4* __restrict__ xt,
        const float* __restrict__ wgt, uint4* __restrict__ wB)
{
    if (blockIdx.y == NB) {
        if (blockIdx.x < 9) {
            int idx = blockIdx.x * 256 + threadIdx.x;   // s*64 + l
            int s = idx >> 6, l = idx & 63;
            int tap = s >> 2, ci0 = (s & 3) * 16;
            int oc = l & 31, kg = l >> 5;
            unsigned r[4];
#pragma unroll
            for (int jp = 0; jp < 4; jp++) {
                float v0 = 0.f, v1 = 0.f;
                int ci = ci0 + kg * 8 + jp * 2;
                if (oc < OC) {
                    v0 = wgt[(oc * CIN + ci) * 9 + tap];
                    v1 = wgt[(oc * CIN + ci + 1) * 9 + tap];
                }
                r[jp] = pack_bf16(v0, v1);
            }
            wB[idx] = make_uint4(r[0], r[1], r[2], r[3]);
        }
        return;
    }

    __shared__ uint4 bufq[2048];          // 32 KB
    unsigned* buf = (unsigned*)bufq;

    const int h = blockIdx.x, n = blockIdx.y;
    const int t = threadIdx.x;
    const int tpx = t & 63;
    const int cg = t >> 6;
    const int px0 = tpx * 4;
    const unsigned swz = ((unsigned)tpx & 7u) << 2;

    const float* xrow = x + ((size_t)n * CIN * H + h) * W;

#pragma unroll
    for (int ii = 0; ii < 4; ii++) {
        const int cq = cg * 4 + ii;
        const float4 A0 = *(const float4*)(xrow + (size_t)(4 * cq + 0) * HW + px0);
        const float4 A1 = *(const float4*)(xrow + (size_t)(4 * cq + 1) * HW + px0);
        const float4 A2 = *(const float4*)(xrow + (size_t)(4 * cq + 2) * HW + px0);
        const float4 A3 = *(const float4*)(xrow + (size_t)(4 * cq + 3) * HW + px0);
        const float a0[4] = {A0.x, A0.y, A0.z, A0.w};
        const float a1[4] = {A1.x, A1.y, A1.z, A1.w};
        const float a2[4] = {A2.x, A2.y, A2.z, A2.w};
        const float a3[4] = {A3.x, A3.y, A3.z, A3.w};
#pragma unroll
        for (int i = 0; i < 4; i++) {
            unsigned lo = pack_bf16(a0[i], a1[i]);
            unsigned hi = pack_bf16(a2[i], a3[i]);
            unsigned widx = (unsigned)(px0 + i) * 32u + ((unsigned)(2 * cq) ^ swz);
            *(uint2*)&buf[widx] = make_uint2(lo, hi);
        }
    }
    __syncthreads();

    const size_t rowbase = ((size_t)(n * H + h)) * W * 8;
#pragma unroll
    for (int i = 0; i < 8; i++) {
        int flat = i * 256 + t;
        int px = flat >> 3, j = flat & 7;
        unsigned sw = (((unsigned)px >> 2) & 7u) << 2;
        uint4 v = *(const uint4*)&buf[(unsigned)px * 32u + (((unsigned)(4 * j)) ^ sw)];
        xt[rowbase + flat] = v;
    }
}

// ---------------------------------------------------------------------------
// Kernel A: persistent-tile implicit-GEMM bf16 MFMA conv.
// Block = 8 rows x 64 cols = 4 tiles of 16x8. A in LDS (3-buffer rotation,
// ONE barrier per tile); B in REGISTERS (36 uint4/lane, static indices).
// Per-block BN partials to part[36][NWB] (no global atomics).
// XCD decode: cls = bid&7 = (n, h-half).
// D (32x32): col = lane&31 = oc, row = (reg&3)+8*(reg>>2)+4*(lane>>5) = pixel.
// ---------------------------------------------------------------------------
__global__ __launch_bounds__(256, 2) void conv_kernel(
        const uint4* __restrict__ xt, const uint4* __restrict__ wB,
        float* __restrict__ sigma_s, float* __restrict__ part)
{
    __shared__ unsigned alds[3][AWORDS];   // 3 x 25,920 B = 77.8 KB
    __shared__ float sred[2 * OC];

    const int tid = threadIdx.x;
    const int lane = tid & 63;

    // decode: cls = (n, hhalf); L -> (ht_local, wquad)
    const int b = blockIdx.x;
    const int cls = b & 7;
    const int L = b >> 3;                  // 0..63
    const int n = cls >> 1;
    const int hhalf = cls & 1;
    const int ht = L >> 2;                 // 0..15
    const int wq = L & 3;                  // 0..3
    const int h0 = (hhalf * 16 + ht) * TSY;
    const int w0 = wq * (NTILE * TSX);

    if (tid < 2 * OC) sred[tid] = 0.f;

    // ---- B fragments -> registers (static indices; zeros for oc>=18) ----
    uint4 breg[36];
#pragma unroll
    for (int s = 0; s < 36; s++) breg[s] = wB[s * 64 + lane];

    // ---- t-invariant A staging map (6 elements/thread) ----
    size_t gbase[6];
    int    alw[6], apx[6];
    bool   av[6];
#pragma unroll
    for (int i = 0; i < 6; i++) {
        int e = tid + i * 256;
        av[i] = e < 1440;
        if (!av[i]) e = 1439;
        int row = e / 144;
        int rr  = e - row * 144;
        int px  = rr >> 3;
        int c   = rr & 7;
        int gh  = refl(h0 + row - 1, H);
        gbase[i] = (size_t)(n * H + gh) * W * 8 + c;
        apx[i]  = px;
        alw[i]  = row * ROWW + px * WPX + c * 4;
    }

    // ---- stage A tile 0 ----
    {
        uint4 ast[6];
#pragma unroll
        for (int i = 0; i < 6; i++) {
            if (av[i]) {
                int gw = refl(w0 + apx[i] - 1, W);
                ast[i] = xt[gbase[i] + (size_t)gw * 8];
            }
        }
#pragma unroll
        for (int i = 0; i < 6; i++)
            if (av[i]) *(uint4*)&alds[0][alw[i]] = ast[i];
    }
    __syncthreads();

    // ---- lane geometry ----
    const int wv = tid >> 6;
    const int m = lane & 31;
    const int kg = lane >> 5;
    const int pr = m >> 4, pc = m & 15;
    const int r0 = 2 * wv + pr;
    const int abase = r0 * ROWW + pc * WPX + kg * 4;

    float s_acc = 0.f, ss_acc = 0.f;
    const int oy = (h0 >> 1) + wv;
    const size_t pb_n = (size_t)n * OC;

#pragma unroll 1
    for (int t = 0; t < NTILE; t++) {
        // issue next tile's A loads (held in regs across compute)
        uint4 pfa[6];
        if (t + 1 < NTILE) {
            const int w0n = w0 + (t + 1) * TSX;
#pragma unroll
            for (int i = 0; i < 6; i++) {
                if (av[i]) {
                    int gw = refl(w0n + apx[i] - 1, W);
                    pfa[i] = xt[gbase[i] + (size_t)gw * 8];
                }
            }
        }

        // compute tile t from alds[t%3]  (B from registers)
        const unsigned* ap = &alds[t % 3][abase];
        f32x16 acc = {};
#pragma unroll
        for (int g = 0; g < 9; g++) {
            const int kh = g / 3, kw = g % 3;
#pragma unroll
            for (int q = 0; q < 4; q++) {
                uint4 af = *(const uint4*)(ap + kh * ROWW + kw * WPX + q * 8);
                acc = __builtin_amdgcn_mfma_f32_32x32x16_bf16(
                        __builtin_bit_cast(bf16x8, af),
                        __builtin_bit_cast(bf16x8, breg[g * 4 + q]), acc, 0, 0, 0);
            }
        }

        // stats accumulate + strided sigma store
#pragma unroll
        for (int rr = 0; rr < 16; rr++) {
            s_acc  += acc[rr];
            ss_acc += acc[rr] * acc[rr];
        }
        if (m < OC) {
            const int ox0 = (w0 + t * TSX) >> 1;
            const size_t pbase = ((pb_n + m) * OH + oy) * OW;
#pragma unroll
            for (int rr = 0; rr < 16; rr++) {
                int p = (rr & 3) + 8 * (rr >> 2) + 4 * kg;
                if (p < 16 && (p & 1) == 0)
                    sigma_s[pbase + ox0 + (p >> 1)] = acc[rr];
            }
        }

        // write next tile into rotation buffer (last reader finished 2 barriers ago)
        if (t + 1 < NTILE) {
#pragma unroll
            for (int i = 0; i < 6; i++)
                if (av[i]) *(uint4*)&alds[(t + 1) % 3][alw[i]] = pfa[i];
        }
        __syncthreads();
    }

    // ---- BN partials: block-local reduce, one plain store per channel ----
    s_acc  += __shfl_xor(s_acc, 32);
    ss_acc += __shfl_xor(ss_acc, 32);
    if (kg == 0 && m < OC) {
        atomicAdd(&sred[m], s_acc);
        atomicAdd(&sred[OC + m], ss_acc);
    }
    __syncthreads();
    if (tid < 2 * OC) part[tid * NWB + blockIdx.x] = sred[tid];
}

// ---------------------------------------------------------------------------
// Kernel B: reduce per-block partials + finalize BN -> scale/shift.
// ---------------------------------------------------------------------------
__global__ __launch_bounds__(256) void bn_kernel(
        const float* __restrict__ gamma, const float* __restrict__ beta,
        const float* __restrict__ part, float* __restrict__ stats)
{
    __shared__ float red[8];
    const int c = blockIdx.x;
    const int tid = threadIdx.x;

    float s  = part[c * NWB + tid]        + part[c * NWB + 256 + tid];
    float ss = part[(OC + c) * NWB + tid] + part[(OC + c) * NWB + 256 + tid];
#pragma unroll
    for (int off = 32; off > 0; off >>= 1) {
        s  += __shfl_down(s, off);
        ss += __shfl_down(ss, off);
    }
    const int wid = tid >> 6, lanez = tid & 63;
    if (lanez == 0) { red[wid] = s; red[4 + wid] = ss; }
    __syncthreads();
    if (tid == 0) {
        float S  = red[0] + red[1] + red[2] + red[3];
        float SS = red[4] + red[5] + red[6] + red[7];
        float cnt = (float)NB * H * W;
        float mean = S / cnt;
        float var  = SS / cnt - mean * mean;
        float sc   = gamma[c] * rsqrtf(var + EPS);
        stats[36 + c] = sc;
        stats[54 + c] = beta[c] - mean * sc;
    }
}

// ---------------------------------------------------------------------------
// Kernel C: BN-affine + softmax(18) + 9-tap aggregation from NHWC bf16.
// ---------------------------------------------------------------------------
__global__ __launch_bounds__(256) void out_kernel(
        const uint4* __restrict__ xt, const float* __restrict__ sigma_s,
        const float* __restrict__ stats, float* __restrict__ out)
{
    __shared__ float p_lds[OC][64];

    const int oh = blockIdx.x;
    const int n  = blockIdx.y >> 1;
    const int ow0 = (blockIdx.y & 1) * 64;
    const int h  = 2 * oh;
    const int tid = threadIdx.x;

    for (int i = tid; i < OC * 64; i += 256) {
        int ch = i >> 6, owl = i & 63;
        float v = sigma_s[((size_t)(n * OC + ch) * OH + oh) * OW + ow0 + owl];
        p_lds[ch][owl] = v * stats[36 + ch] + stats[54 + ch];
    }
    __syncthreads();

    if (tid < 64) {
        int owl = tid;
        float mx = -1e30f;
#pragma unroll
        for (int ch = 0; ch < OC; ch++) mx = fmaxf(mx, p_lds[ch][owl]);
        float e[OC], sum = 0.f;
#pragma unroll
        for (int ch = 0; ch < OC; ch++) { e[ch] = __expf(p_lds[ch][owl] - mx); sum += e[ch]; }
        float inv = 1.f / sum;
#pragma unroll
        for (int ch = 0; ch < OC; ch++) p_lds[ch][owl] = e[ch] * inv;
    }
    __syncthreads();

    int ihs[3];
#pragma unroll
    for (int kh = 0; kh < 3; kh++) ihs[kh] = refl(h - 1 + kh, H);

#pragma unroll
    for (int it = 0; it < 2; it++) {
        const int flat = it * 256 + tid;
        const int c8 = flat & 7;
        const int owl = flat >> 3;
        const int ow = ow0 + owl;
        const int g = (c8 >= 4) ? 1 : 0;

        float a[8];
#pragma unroll
        for (int j = 0; j < 8; j++) a[j] = 0.f;

#pragma unroll
        for (int kh = 0; kh < 3; kh++) {
            const size_t rb = ((size_t)(n * H + ihs[kh])) * W * 8;
#pragma unroll
            for (int kw = 0; kw < 3; kw++) {
                const int iw = refl(2 * ow - 1 + kw, W);
                const float p = p_lds[g * 9 + kh * 3 + kw][owl];
                uint4 v = xt[rb + (size_t)iw * 8 + c8];
                const unsigned uu[4] = {v.x, v.y, v.z, v.w};
#pragma unroll
                for (int q = 0; q < 4; q++) {
                    float lo = __builtin_bit_cast(float, uu[q] << 16);
                    float hi = __builtin_bit_cast(float, uu[q] & 0xffff0000u);
                    a[2 * q]     = fmaf(p, lo, a[2 * q]);
                    a[2 * q + 1] = fmaf(p, hi, a[2 * q + 1]);
                }
            }
        }

        const size_t ob = ((size_t)(n * CIN + c8 * 8) * OH + oh) * OW + ow;
#pragma unroll
        for (int j = 0; j < 8; j++)
            out[ob + (size_t)j * OH * OW] = a[j];
    }
}

// ---------------------------------------------------------------------------
extern "C" void kernel_launch(void* const* d_in, const int* in_sizes, int n_in,
                              void* d_out, int out_size, void* d_ws, size_t ws_size,
                              hipStream_t stream) {
    const float* x     = (const float*)d_in[0];
    const float* cw    = (const float*)d_in[1];
    const float* gamma = (const float*)d_in[2];
    const float* beta  = (const float*)d_in[3];
    float* out = (float*)d_out;
    float* ws  = (float*)d_ws;

    float* stats   = ws;                                    // 256 floats
    float* sigma_s = ws + 256;                              // 1,179,648 floats
    uint4* wBp     = (uint4*)(sigma_s + (size_t)NB * OC * OH * OW);   // 2304 uint4
    uint4* xtp     = wBp + 36 * 64;                         // 2,097,152 uint4
    float* part    = (float*)(xtp + (size_t)NB * H * W * 8);          // 36*512 floats

    dim3 gT(H, NB + 1);   // y==NB does the weight repack
    nhwc_kernel<<<gT, 256, 0, stream>>>(x, xtp, cw, wBp);

    conv_kernel<<<dim3(NWB), 256, 0, stream>>>(xtp, wBp, sigma_s, part);

    bn_kernel<<<OC, 256, 0, stream>>>(gamma, beta, part, stats);

    dim3 gC(OH, NB * 2);
    out_kernel<<<gC, 256, 0, stream>>>(xtp, sigma_s, stats, out);
}